// Round 6
// baseline (238.481 us; speedup 1.0000x reference)
//
#include <hip/hip_runtime.h>
#include <math.h>

#define NNODES 50000
#define NEDGES 800000
#define ETOT   850000            // edges + self loops
#define F      64
#define NB     782               // ceil(NNODES/64) buckets of 64 nodes
#define LIN_BLOCKS  3125         // 16 nodes / block
#define AGG_BLOCKS  12500        // 4 nodes / block (wave per node)
#define SBLK   128               // staging blocks
#define SIT    26                // edges/thread in staging
#define SEPB   (256 * SIT)       // 6656 edges per staging block

typedef unsigned short u16;
typedef unsigned int   u32;

// pack two f32 -> two bf16 (RNE)
__device__ __forceinline__ u32 f2bf2(float a, float b) {
    u32 ua = __float_as_uint(a), ub = __float_as_uint(b);
    ua = (ua + 0x7FFFu + ((ua >> 16) & 1u)) >> 16;
    ub = (ub + 0x7FFFu + ((ub >> 16) & 1u)) >> 16;
    return ua | (ub << 16);
}

__device__ __forceinline__ float4 load4f(const float* p) { return *(const float4*)p; }
__device__ __forceinline__ float4 load4f(const u16* p) {
    uint2 u = *(const uint2*)p;
    float4 v;
    v.x = __uint_as_float(u.x << 16); v.y = __uint_as_float(u.x & 0xFFFF0000u);
    v.z = __uint_as_float(u.y << 16); v.w = __uint_as_float(u.y & 0xFFFF0000u);
    return v;
}

// shared-memory layout for the linear body (also aliased by the count path)
struct LinSmem {
    float Ws[F * F];        // 16 KB
    float xs[16][F + 1];
    float asv[F], adv[F];
};

// ---------------------------------------------------------------------------
// Linear body: h16 = bf16(x @ W) ; as_ = (xW).a_src ; ad_ = (xW).a_dst
// 16 nodes / block; quarter-wave (16 lanes) per node, 4 output cols per lane.
// ---------------------------------------------------------------------------
template <typename TIN>
__device__ __forceinline__ void linear_body(
    LinSmem& sm,
    const TIN* __restrict__ x, const float* __restrict__ W,
    const float* __restrict__ a_src, const float* __restrict__ a_dst,
    u16* __restrict__ h16, float* __restrict__ as_, float* __restrict__ ad_,
    int blk)
{
    const int tid = threadIdx.x;
    const int wv  = tid >> 6;
    const int ln  = tid & 63;
    const int q   = ln >> 4;
    const int fl4 = (ln & 15) * 4;
    const int nb  = wv * 4 + q;
    const int node = blk * 16 + nb;

    for (int i = tid * 4; i < F * F; i += 1024)
        *(float4*)&sm.Ws[i] = *(const float4*)&W[i];
    if (tid < F) { sm.asv[tid] = a_src[tid]; sm.adv[tid] = a_dst[tid]; }
    {
        const int n  = tid >> 4;
        const int c4 = (tid & 15) * 4;
        const float4 v = load4f(&x[(size_t)(blk * 16 + n) * F + c4]);
        sm.xs[n][c4] = v.x; sm.xs[n][c4+1] = v.y;
        sm.xs[n][c4+2] = v.z; sm.xs[n][c4+3] = v.w;
    }
    __syncthreads();

    float4 acc = {0.f, 0.f, 0.f, 0.f};
#pragma unroll
    for (int k = 0; k < F; ++k) {
        const float xv = sm.xs[nb][k];
        const float4 w = *(const float4*)&sm.Ws[k * F + fl4];
        acc.x = fmaf(xv, w.x, acc.x);
        acc.y = fmaf(xv, w.y, acc.y);
        acc.z = fmaf(xv, w.z, acc.z);
        acc.w = fmaf(xv, w.w, acc.w);
    }

    uint2 p;
    p.x = f2bf2(acc.x, acc.y);
    p.y = f2bf2(acc.z, acc.w);
    *(uint2*)(h16 + (size_t)node * F + fl4) = p;

    float vs = acc.x * sm.asv[fl4] + acc.y * sm.asv[fl4+1]
             + acc.z * sm.asv[fl4+2] + acc.w * sm.asv[fl4+3];
    float vd = acc.x * sm.adv[fl4] + acc.y * sm.adv[fl4+1]
             + acc.z * sm.adv[fl4+2] + acc.w * sm.adv[fl4+3];
#pragma unroll
    for (int off = 1; off < 16; off <<= 1) {
        vs += __shfl_xor(vs, off, 64);
        vd += __shfl_xor(vd, off, 64);
    }
    if ((ln & 15) == 0) { as_[node] = vs; ad_[node] = vd; }
}

// ---------------------------------------------------------------------------
// K1: blocks [0,SBLK): per-BUCKET edge counts (LDS-reduced -> ~100K global
//     atomics onto 782 words, vs 850K onto 50000 before).
//     blocks [SBLK..): layer-1 linear.
// ---------------------------------------------------------------------------
__global__ __launch_bounds__(256) void linear1_count(
    const float* __restrict__ x, const float* __restrict__ W,
    const float* __restrict__ a_src, const float* __restrict__ a_dst,
    u16* __restrict__ h16, float* __restrict__ as_, float* __restrict__ ad_,
    const int* __restrict__ dst, int* __restrict__ btot)
{
    __shared__ LinSmem sm;
    if (blockIdx.x < SBLK) {
        int* cnt = (int*)&sm;              // NB ints (3128 B) alias LinSmem
        for (int i = threadIdx.x; i < NB; i += 256) cnt[i] = 0;
        __syncthreads();
        const int base = blockIdx.x * SEPB;
#pragma unroll
        for (int it = 0; it < SIT; ++it) {
            const int e = base + it * 256 + threadIdx.x;
            if (e < ETOT) {
                const int d = (e < NEDGES) ? dst[e] : (e - NEDGES);
                atomicAdd(&cnt[d >> 6], 1);
            }
        }
        __syncthreads();
        for (int i = threadIdx.x; i < NB; i += 256)
            if (cnt[i]) atomicAdd(&btot[i], cnt[i]);
        return;
    }
    linear_body<float>(sm, x, W, a_src, a_dst, h16, as_, ad_, blockIdx.x - SBLK);
}

// layer-2 linear: bf16 input
__global__ __launch_bounds__(256) void node_linear2(
    const u16* __restrict__ x, const float* __restrict__ W,
    const float* __restrict__ a_src, const float* __restrict__ a_dst,
    u16* __restrict__ h16, float* __restrict__ as_, float* __restrict__ ad_)
{
    __shared__ LinSmem sm;
    linear_body<u16>(sm, x, W, a_src, a_dst, h16, as_, ad_, blockIdx.x);
}

// ---------------------------------------------------------------------------
// K2: exclusive scan of bucket totals -> sbase[NB+1]; init gcur = sbase.
// ---------------------------------------------------------------------------
__global__ __launch_bounds__(1024) void sbase_scan(
    const int* __restrict__ btot, int* __restrict__ sbase, int* __restrict__ gcur)
{
    __shared__ int s[1024];
    const int t = threadIdx.x;
    const int v = (t < NB) ? btot[t] : 0;
    s[t] = v;
    __syncthreads();
    for (int off = 1; off < 1024; off <<= 1) {
        int u = (t >= off) ? s[t - off] : 0;
        __syncthreads();
        s[t] += u;
        __syncthreads();
    }
    if (t < NB) { const int e = s[t] - v; sbase[t] = e; gcur[t] = e; }
    if (t == 0) sbase[NB] = ETOT;
}

// ---------------------------------------------------------------------------
// K3: stage edges grouped by 64-node bucket. Packed entry (d&63)<<16 | src.
// LDS counts; ONE global reservation per (block,bucket) -> contiguous runs.
// ---------------------------------------------------------------------------
__global__ __launch_bounds__(256) void stage_edges(
    const int* __restrict__ src, const int* __restrict__ dst,
    int* __restrict__ gcur, u32* __restrict__ stg)
{
    __shared__ int cnt[NB];
    __shared__ int lcur[NB];
    for (int i = threadIdx.x; i < NB; i += 256) cnt[i] = 0;
    __syncthreads();
    const int base = blockIdx.x * SEPB;
#pragma unroll
    for (int it = 0; it < SIT; ++it) {
        const int e = base + it * 256 + threadIdx.x;
        if (e < ETOT) {
            const int d = (e < NEDGES) ? dst[e] : (e - NEDGES);
            atomicAdd(&cnt[d >> 6], 1);
        }
    }
    __syncthreads();
    for (int i = threadIdx.x; i < NB; i += 256)
        lcur[i] = cnt[i] ? atomicAdd(&gcur[i], cnt[i]) : 0;
    __syncthreads();
#pragma unroll
    for (int it = 0; it < SIT; ++it) {
        const int e = base + it * 256 + threadIdx.x;
        if (e < ETOT) {
            int s, d;
            if (e < NEDGES) { s = src[e]; d = dst[e]; }
            else            { s = e - NEDGES; d = s; }
            const int p = atomicAdd(&lcur[d >> 6], 1);
            stg[p] = ((u32)(d & 63) << 16) | (u32)s;
        }
    }
}

// ---------------------------------------------------------------------------
// K4: per bucket: count 64 node histogram from dense segment, 64-lane
// shfl_up scan -> rowptr (coalesced write), scatter u16 src into csr.
// Replaces the global per-node hist + 3-kernel scan entirely.
// ---------------------------------------------------------------------------
__global__ __launch_bounds__(256) void bucket_csr_rp(
    const int* __restrict__ sbase, const u32* __restrict__ stg,
    u16* __restrict__ csr, int* __restrict__ rowptr)
{
    __shared__ int cnt[64];
    const int b = blockIdx.x;
    const int nbase = b << 6;
    const int nr = (NNODES - nbase < 64) ? (NNODES - nbase) : 64;
    const int beg = sbase[b], end = sbase[b + 1];

    if (threadIdx.x < 64) cnt[threadIdx.x] = 0;
    __syncthreads();
    for (int i = beg + threadIdx.x; i < end; i += 256)
        atomicAdd(&cnt[stg[i] >> 16], 1);
    __syncthreads();
    if (threadIdx.x < 64) {
        const int v = cnt[threadIdx.x];
        int incl = v;
#pragma unroll
        for (int off = 1; off < 64; off <<= 1) {
            const int t = __shfl_up(incl, off, 64);
            if (threadIdx.x >= off) incl += t;
        }
        const int pos = beg + incl - v;          // global exclusive prefix
        cnt[threadIdx.x] = pos;                  // reuse as scatter cursor
        if (threadIdx.x < nr) rowptr[nbase + threadIdx.x] = pos;
        if (b == NB - 1 && threadIdx.x == 0) rowptr[NNODES] = ETOT;
    }
    __syncthreads();
    for (int i = beg + threadIdx.x; i < end; i += 256) {
        const u32 pk = stg[i];
        const int pos = atomicAdd(&cnt[pk >> 16], 1);
        csr[pos] = (u16)(pk & 0xFFFFu);
    }
}

// ---------------------------------------------------------------------------
// Fused softmax + aggregate + bias + LeakyReLU(0.01).
// Wave per node; 8 lanes per edge (8 bf16 features / lane) -> 8 edges in
// flight per wave. MODE 0: write bf16 hmid. MODE 1: +residual, write f32 out.
// ---------------------------------------------------------------------------
template<int MODE>
__global__ __launch_bounds__(256) void gat_agg(
    const int* __restrict__ rowptr, const u16* __restrict__ csr,
    const u16* __restrict__ h16, const float* __restrict__ as_,
    const float* __restrict__ ad_, const float* __restrict__ bias,
    u16* __restrict__ hout16,
    const float* __restrict__ resid, float* __restrict__ out)
{
    const int tid  = threadIdx.x;
    const int wv   = tid >> 6;
    const int ln   = tid & 63;
    const int node = blockIdx.x * 4 + wv;
    const int g    = ln >> 3;      // edge slot 0..7
    const int l    = ln & 7;       // 16B chunk of the 128B bf16 row

    const float ad_n = ad_[node];
    const int beg = rowptr[node];
    const int end = rowptr[node + 1];

    float a0=0.f,a1=0.f,a2=0.f,a3=0.f,a4=0.f,a5=0.f,a6=0.f,a7=0.f;
    float z = 0.f;
    for (int i = beg + g; i < end; i += 8) {
        const int s = csr[i];
        float t = as_[s] + ad_n;
        t = (t > 0.f) ? t : 0.2f * t;
        const float ev = __expf(t);
        const uint4 hv = ((const uint4*)(h16 + (size_t)s * F))[l];
        z += ev;
        a0 = fmaf(ev, __uint_as_float(hv.x << 16),          a0);
        a1 = fmaf(ev, __uint_as_float(hv.x & 0xFFFF0000u),  a1);
        a2 = fmaf(ev, __uint_as_float(hv.y << 16),          a2);
        a3 = fmaf(ev, __uint_as_float(hv.y & 0xFFFF0000u),  a3);
        a4 = fmaf(ev, __uint_as_float(hv.z << 16),          a4);
        a5 = fmaf(ev, __uint_as_float(hv.z & 0xFFFF0000u),  a5);
        a6 = fmaf(ev, __uint_as_float(hv.w << 16),          a6);
        a7 = fmaf(ev, __uint_as_float(hv.w & 0xFFFF0000u),  a7);
    }
#pragma unroll
    for (int off = 8; off < 64; off <<= 1) {
        a0 += __shfl_xor(a0, off, 64); a1 += __shfl_xor(a1, off, 64);
        a2 += __shfl_xor(a2, off, 64); a3 += __shfl_xor(a3, off, 64);
        a4 += __shfl_xor(a4, off, 64); a5 += __shfl_xor(a5, off, 64);
        a6 += __shfl_xor(a6, off, 64); a7 += __shfl_xor(a7, off, 64);
        z  += __shfl_xor(z,  off, 64);
    }

    if (g == 0) {
        const float inv = 1.f / (z + 1e-16f);
        const float4 b0 = *(const float4*)&bias[l * 8];
        const float4 b1 = *(const float4*)&bias[l * 8 + 4];
        float v0 = a0 * inv + b0.x, v1 = a1 * inv + b0.y;
        float v2 = a2 * inv + b0.z, v3 = a3 * inv + b0.w;
        float v4 = a4 * inv + b1.x, v5 = a5 * inv + b1.y;
        float v6 = a6 * inv + b1.z, v7 = a7 * inv + b1.w;
        v0 = (v0 > 0.f) ? v0 : 0.01f * v0;  v1 = (v1 > 0.f) ? v1 : 0.01f * v1;
        v2 = (v2 > 0.f) ? v2 : 0.01f * v2;  v3 = (v3 > 0.f) ? v3 : 0.01f * v3;
        v4 = (v4 > 0.f) ? v4 : 0.01f * v4;  v5 = (v5 > 0.f) ? v5 : 0.01f * v5;
        v6 = (v6 > 0.f) ? v6 : 0.01f * v6;  v7 = (v7 > 0.f) ? v7 : 0.01f * v7;
        if (MODE == 0) {
            uint4 p;
            p.x = f2bf2(v0, v1); p.y = f2bf2(v2, v3);
            p.z = f2bf2(v4, v5); p.w = f2bf2(v6, v7);
            ((uint4*)(hout16 + (size_t)node * F))[l] = p;
        } else {
            const float4 r0 = *(const float4*)(resid + (size_t)node * F + l * 8);
            const float4 r1 = *(const float4*)(resid + (size_t)node * F + l * 8 + 4);
            float4 o0, o1;
            o0.x = v0 + r0.x; o0.y = v1 + r0.y; o0.z = v2 + r0.z; o0.w = v3 + r0.w;
            o1.x = v4 + r1.x; o1.y = v5 + r1.y; o1.z = v6 + r1.z; o1.w = v7 + r1.w;
            *(float4*)(out + (size_t)node * F + l * 8)     = o0;
            *(float4*)(out + (size_t)node * F + l * 8 + 4) = o1;
        }
    }
}

extern "C" void kernel_launch(void* const* d_in, const int* in_sizes, int n_in,
                              void* d_out, int out_size, void* d_ws, size_t ws_size,
                              hipStream_t stream)
{
    const float* x   = (const float*)d_in[0];
    const int*   ei  = (const int*)  d_in[1];   // [2, NEDGES] row-major
    const float* W0  = (const float*)d_in[2];
    const float* as0 = (const float*)d_in[3];
    const float* ad0 = (const float*)d_in[4];
    const float* b0  = (const float*)d_in[5];
    const float* W1  = (const float*)d_in[6];
    const float* as1 = (const float*)d_in[7];
    const float* ad1 = (const float*)d_in[8];
    const float* b1  = (const float*)d_in[9];
    float* out = (float*)d_out;

    const int* src = ei;
    const int* dst = ei + NEDGES;

    // workspace carve-up (~19 MB)
    char* ws = (char*)d_ws;
    u16*   h16    = (u16*)ws;   ws += (size_t)NNODES * F * 2;
    u16*   hmid16 = (u16*)ws;   ws += (size_t)NNODES * F * 2;
    float* as_    = (float*)ws; ws += (size_t)NNODES * 4;
    float* ad_    = (float*)ws; ws += (size_t)NNODES * 4;
    float* as2    = (float*)ws; ws += (size_t)NNODES * 4;
    float* ad2    = (float*)ws; ws += (size_t)NNODES * 4;
    int*   rowptr = (int*)ws;   ws += (size_t)(NNODES + 1) * 4;
    int*   btot   = (int*)ws;   ws += (size_t)NB * 4;
    int*   sbase  = (int*)ws;   ws += (size_t)(NB + 1) * 4;
    int*   gcur   = (int*)ws;   ws += (size_t)NB * 4;
    u32*   stg    = (u32*)ws;   ws += (size_t)ETOT * 4;
    u16*   csr    = (u16*)ws;   ws += (size_t)ETOT * 2;

    hipMemsetAsync(btot, 0, (size_t)NB * 4, stream);
    linear1_count<<<SBLK + LIN_BLOCKS, 256, 0, stream>>>(
        x, W0, as0, ad0, h16, as_, ad_, dst, btot);
    sbase_scan<<<1, 1024, 0, stream>>>(btot, sbase, gcur);
    stage_edges<<<SBLK, 256, 0, stream>>>(src, dst, gcur, stg);
    bucket_csr_rp<<<NB, 256, 0, stream>>>(sbase, stg, csr, rowptr);

    // layer 1 aggregate -> bf16 hmid
    gat_agg<0><<<AGG_BLOCKS, 256, 0, stream>>>(rowptr, csr, h16, as_, ad_,
                                               b0, hmid16, nullptr, nullptr);
    // layer 2 linear (bf16 in) -- h16 safely reused (prev reader done)
    node_linear2<<<LIN_BLOCKS, 256, 0, stream>>>(hmid16, W1, as1, ad1, h16, as2, ad2);
    // layer 2 aggregate + residual -> out
    gat_agg<1><<<AGG_BLOCKS, 256, 0, stream>>>(rowptr, csr, h16, as2, ad2,
                                               b1, nullptr, x, out);
}

// Round 7
// 192.777 us; speedup vs baseline: 1.2371x; 1.2371x over previous
//
#include <hip/hip_runtime.h>
#include <math.h>

#define NNODES 50000
#define NEDGES 800000
#define ETOT   850000            // edges + self loops
#define F      64
#define NB     782               // ceil(NNODES/64) buckets of 64 nodes
#define CAP    1408              // fixed slots per bucket (max count ~1200, 6 sigma margin)
#define LIN_BLOCKS 3125          // 16 nodes / block
#define AGG_BLOCKS 12500         // 4 nodes / block (wave per node)
#define SBLK   256               // staging blocks (1 per CU)
#define SIT    13                // edges/thread in staging
#define SEPB   (256 * SIT)       // 3328 edges per staging block

typedef unsigned short u16;
typedef unsigned int   u32;

// pack two f32 -> two bf16 (RNE)
__device__ __forceinline__ u32 f2bf2(float a, float b) {
    u32 ua = __float_as_uint(a), ub = __float_as_uint(b);
    ua = (ua + 0x7FFFu + ((ua >> 16) & 1u)) >> 16;
    ub = (ub + 0x7FFFu + ((ub >> 16) & 1u)) >> 16;
    return ua | (ub << 16);
}

// shared-memory layout for the linear body (aliased by the stage path)
struct LinSmem {
    float Ws[F * F];        // 16 KB
    float xs[16][F + 1];
    float asv[F], adv[F];
};

// ---------------------------------------------------------------------------
// Linear body: h16 = bf16(x @ W) ; as_ = (xW).a_src ; ad_ = (xW).a_dst
// 16 nodes / block; quarter-wave (16 lanes) per node, 4 output cols per lane.
// ---------------------------------------------------------------------------
__device__ __forceinline__ void linear_body(
    LinSmem& sm,
    const float* __restrict__ x, const float* __restrict__ W,
    const float* __restrict__ a_src, const float* __restrict__ a_dst,
    u16* __restrict__ h16, float* __restrict__ as_, float* __restrict__ ad_,
    int blk)
{
    const int tid = threadIdx.x;
    const int wv  = tid >> 6;
    const int ln  = tid & 63;
    const int q   = ln >> 4;
    const int fl4 = (ln & 15) * 4;
    const int nb  = wv * 4 + q;
    const int node = blk * 16 + nb;

    for (int i = tid * 4; i < F * F; i += 1024)
        *(float4*)&sm.Ws[i] = *(const float4*)&W[i];
    if (tid < F) { sm.asv[tid] = a_src[tid]; sm.adv[tid] = a_dst[tid]; }
    {
        const int n  = tid >> 4;
        const int c4 = (tid & 15) * 4;
        const float4 v = *(const float4*)&x[(size_t)(blk * 16 + n) * F + c4];
        sm.xs[n][c4] = v.x; sm.xs[n][c4+1] = v.y;
        sm.xs[n][c4+2] = v.z; sm.xs[n][c4+3] = v.w;
    }
    __syncthreads();

    float4 acc = {0.f, 0.f, 0.f, 0.f};
#pragma unroll
    for (int k = 0; k < F; ++k) {
        const float xv = sm.xs[nb][k];
        const float4 w = *(const float4*)&sm.Ws[k * F + fl4];
        acc.x = fmaf(xv, w.x, acc.x);
        acc.y = fmaf(xv, w.y, acc.y);
        acc.z = fmaf(xv, w.z, acc.z);
        acc.w = fmaf(xv, w.w, acc.w);
    }

    uint2 p;
    p.x = f2bf2(acc.x, acc.y);
    p.y = f2bf2(acc.z, acc.w);
    *(uint2*)(h16 + (size_t)node * F + fl4) = p;

    float vs = acc.x * sm.asv[fl4] + acc.y * sm.asv[fl4+1]
             + acc.z * sm.asv[fl4+2] + acc.w * sm.asv[fl4+3];
    float vd = acc.x * sm.adv[fl4] + acc.y * sm.adv[fl4+1]
             + acc.z * sm.adv[fl4+2] + acc.w * sm.adv[fl4+3];
#pragma unroll
    for (int off = 1; off < 16; off <<= 1) {
        vs += __shfl_xor(vs, off, 64);
        vd += __shfl_xor(vd, off, 64);
    }
    if ((ln & 15) == 0) { as_[node] = vs; ad_[node] = vd; }
}

// ---------------------------------------------------------------------------
// K1: blocks [0,SBLK): stage edges into fixed-CAP bucket regions.
//     blocks [SBLK..): layer-1 linear (stage latency hides under it).
// Reservation: b*CAP + atomicAdd(gcur[b], cnt)  -- no scan needed.
// ---------------------------------------------------------------------------
__global__ __launch_bounds__(256) void stage_linear1(
    const float* __restrict__ x, const float* __restrict__ W,
    const float* __restrict__ a_src, const float* __restrict__ a_dst,
    u16* __restrict__ h16, float* __restrict__ as_, float* __restrict__ ad_,
    const int* __restrict__ src, const int* __restrict__ dst,
    int* __restrict__ gcur, u32* __restrict__ stg)
{
    __shared__ LinSmem sm;
    if (blockIdx.x < SBLK) {
        int* cnt  = (int*)&sm;          // NB ints
        int* lcur = cnt + NB;           // NB ints (6.3 KB total, aliases LinSmem)
        for (int i = threadIdx.x; i < NB; i += 256) cnt[i] = 0;
        __syncthreads();
        const int base = blockIdx.x * SEPB;
#pragma unroll
        for (int it = 0; it < SIT; ++it) {
            const int e = base + it * 256 + threadIdx.x;
            if (e < ETOT) {
                const int d = (e < NEDGES) ? dst[e] : (e - NEDGES);
                atomicAdd(&cnt[d >> 6], 1);
            }
        }
        __syncthreads();
        for (int i = threadIdx.x; i < NB; i += 256)
            lcur[i] = cnt[i] ? (i * CAP + atomicAdd(&gcur[i], cnt[i])) : 0;
        __syncthreads();
#pragma unroll
        for (int it = 0; it < SIT; ++it) {
            const int e = base + it * 256 + threadIdx.x;
            if (e < ETOT) {
                int s, d;
                if (e < NEDGES) { s = src[e]; d = dst[e]; }
                else            { s = e - NEDGES; d = s; }
                const int p = atomicAdd(&lcur[d >> 6], 1);
                stg[p] = ((u32)(d & 63) << 16) | (u32)s;
            }
        }
        return;
    }
    linear_body(sm, x, W, a_src, a_dst, h16, as_, ad_, blockIdx.x - SBLK);
}

// ---------------------------------------------------------------------------
// K2: per bucket: 64-node histogram of its dense segment, shfl_up scan ->
// rowptr/rowcnt, scatter u16 src ids into per-node csr slots.
// ---------------------------------------------------------------------------
__global__ __launch_bounds__(256) void bucket_csr(
    const int* __restrict__ gcur, const u32* __restrict__ stg,
    u16* __restrict__ csr, int* __restrict__ rowptr, int* __restrict__ rowcnt)
{
    __shared__ int cnt[64];
    const int b = blockIdx.x;
    const int nbase = b << 6;
    const int nr  = (NNODES - nbase < 64) ? (NNODES - nbase) : 64;
    const int beg = b * CAP;
    const int m   = gcur[b];          // edges in this bucket

    if (threadIdx.x < 64) cnt[threadIdx.x] = 0;
    __syncthreads();
    for (int i = threadIdx.x; i < m; i += 256)
        atomicAdd(&cnt[stg[beg + i] >> 16], 1);
    __syncthreads();
    if (threadIdx.x < 64) {
        const int v = cnt[threadIdx.x];
        int incl = v;
#pragma unroll
        for (int off = 1; off < 64; off <<= 1) {
            const int t = __shfl_up(incl, off, 64);
            if (threadIdx.x >= off) incl += t;
        }
        const int pos = beg + incl - v;     // exclusive prefix within bucket
        cnt[threadIdx.x] = pos;             // reuse as scatter cursor
        if (threadIdx.x < nr) {
            rowptr[nbase + threadIdx.x] = pos;
            rowcnt[nbase + threadIdx.x] = v;
        }
    }
    __syncthreads();
    for (int i = threadIdx.x; i < m; i += 256) {
        const u32 pk = stg[beg + i];
        const int pos = atomicAdd(&cnt[pk >> 16], 1);
        csr[pos] = (u16)(pk & 0xFFFFu);
    }
}

// ---------------------------------------------------------------------------
// K3/K4: fused softmax + aggregate + bias + LeakyReLU(0.01).
// Wave per node; 8 lanes/edge, loop unrolled x2 -> 16 gather rows in flight.
// MODE 0 epilogue: layer-2 linear fused (row -> LDS -> quarter-wave GEMM vs
//                  LDS W1) -> bf16 h2 + attention dots.
// MODE 1 epilogue: + residual, f32 out.
// ---------------------------------------------------------------------------
template<int MODE>
__global__ __launch_bounds__(256) void gat_agg(
    const int* __restrict__ rowptr, const int* __restrict__ rowcnt,
    const u16* __restrict__ csr, const u16* __restrict__ hin,
    const float* __restrict__ as_, const float* __restrict__ ad_,
    const float* __restrict__ bias,
    const float* __restrict__ Wn, const float* __restrict__ an_s,
    const float* __restrict__ an_d,
    u16* __restrict__ hout, float* __restrict__ as_out, float* __restrict__ ad_out,
    const float* __restrict__ resid, float* __restrict__ out)
{
    __shared__ float Ws[MODE == 0 ? F * F : 1];
    __shared__ float asv[MODE == 0 ? F : 1], adv[MODE == 0 ? F : 1];
    __shared__ float xrow[MODE == 0 ? 4 : 1][F];

    const int tid  = threadIdx.x;
    const int wv   = tid >> 6;
    const int ln   = tid & 63;
    const int node = blockIdx.x * 4 + wv;
    const int g    = ln >> 3;      // edge slot 0..7
    const int l    = ln & 7;       // 16B chunk of the 128B bf16 row

    if constexpr (MODE == 0) {
        for (int i = tid * 4; i < F * F; i += 1024)
            *(float4*)&Ws[i] = *(const float4*)&Wn[i];
        if (tid < F) { asv[tid] = an_s[tid]; adv[tid] = an_d[tid]; }
        __syncthreads();
    }

    const float ad_n = ad_[node];
    const int beg = rowptr[node];
    const int end = beg + rowcnt[node];

    float a0=0.f,a1=0.f,a2=0.f,a3=0.f,a4=0.f,a5=0.f,a6=0.f,a7=0.f;
    float z = 0.f;
    int i = beg + g;
    for (; i + 8 < end; i += 16) {   // two edges in flight per lane-group
        const int s1 = csr[i];
        const int s2 = csr[i + 8];
        const float as1v = as_[s1];
        const float as2v = as_[s2];
        const uint4 h1 = ((const uint4*)(hin + (size_t)s1 * F))[l];
        const uint4 h2 = ((const uint4*)(hin + (size_t)s2 * F))[l];
        float t1 = as1v + ad_n; t1 = (t1 > 0.f) ? t1 : 0.2f * t1;
        float t2 = as2v + ad_n; t2 = (t2 > 0.f) ? t2 : 0.2f * t2;
        const float e1 = __expf(t1);
        const float e2 = __expf(t2);
        z += e1 + e2;
        a0 = fmaf(e1, __uint_as_float(h1.x << 16),         a0);
        a1 = fmaf(e1, __uint_as_float(h1.x & 0xFFFF0000u), a1);
        a2 = fmaf(e1, __uint_as_float(h1.y << 16),         a2);
        a3 = fmaf(e1, __uint_as_float(h1.y & 0xFFFF0000u), a3);
        a4 = fmaf(e1, __uint_as_float(h1.z << 16),         a4);
        a5 = fmaf(e1, __uint_as_float(h1.z & 0xFFFF0000u), a5);
        a6 = fmaf(e1, __uint_as_float(h1.w << 16),         a6);
        a7 = fmaf(e1, __uint_as_float(h1.w & 0xFFFF0000u), a7);
        a0 = fmaf(e2, __uint_as_float(h2.x << 16),         a0);
        a1 = fmaf(e2, __uint_as_float(h2.x & 0xFFFF0000u), a1);
        a2 = fmaf(e2, __uint_as_float(h2.y << 16),         a2);
        a3 = fmaf(e2, __uint_as_float(h2.y & 0xFFFF0000u), a3);
        a4 = fmaf(e2, __uint_as_float(h2.z << 16),         a4);
        a5 = fmaf(e2, __uint_as_float(h2.z & 0xFFFF0000u), a5);
        a6 = fmaf(e2, __uint_as_float(h2.w << 16),         a6);
        a7 = fmaf(e2, __uint_as_float(h2.w & 0xFFFF0000u), a7);
    }
    if (i < end) {                   // at most one tail edge per group
        const int s1 = csr[i];
        float t1 = as_[s1] + ad_n; t1 = (t1 > 0.f) ? t1 : 0.2f * t1;
        const float e1 = __expf(t1);
        const uint4 h1 = ((const uint4*)(hin + (size_t)s1 * F))[l];
        z += e1;
        a0 = fmaf(e1, __uint_as_float(h1.x << 16),         a0);
        a1 = fmaf(e1, __uint_as_float(h1.x & 0xFFFF0000u), a1);
        a2 = fmaf(e1, __uint_as_float(h1.y << 16),         a2);
        a3 = fmaf(e1, __uint_as_float(h1.y & 0xFFFF0000u), a3);
        a4 = fmaf(e1, __uint_as_float(h1.z << 16),         a4);
        a5 = fmaf(e1, __uint_as_float(h1.z & 0xFFFF0000u), a5);
        a6 = fmaf(e1, __uint_as_float(h1.w << 16),         a6);
        a7 = fmaf(e1, __uint_as_float(h1.w & 0xFFFF0000u), a7);
    }
#pragma unroll
    for (int off = 8; off < 64; off <<= 1) {   // butterfly: all lanes get totals
        a0 += __shfl_xor(a0, off, 64); a1 += __shfl_xor(a1, off, 64);
        a2 += __shfl_xor(a2, off, 64); a3 += __shfl_xor(a3, off, 64);
        a4 += __shfl_xor(a4, off, 64); a5 += __shfl_xor(a5, off, 64);
        a6 += __shfl_xor(a6, off, 64); a7 += __shfl_xor(a7, off, 64);
        z  += __shfl_xor(z,  off, 64);
    }

    const float inv = 1.f / (z + 1e-16f);
    const float4 b0v = *(const float4*)&bias[l * 8];
    const float4 b1v = *(const float4*)&bias[l * 8 + 4];
    float v0 = a0 * inv + b0v.x, v1 = a1 * inv + b0v.y;
    float v2 = a2 * inv + b0v.z, v3 = a3 * inv + b0v.w;
    float v4 = a4 * inv + b1v.x, v5 = a5 * inv + b1v.y;
    float v6 = a6 * inv + b1v.z, v7 = a7 * inv + b1v.w;
    v0 = (v0 > 0.f) ? v0 : 0.01f * v0;  v1 = (v1 > 0.f) ? v1 : 0.01f * v1;
    v2 = (v2 > 0.f) ? v2 : 0.01f * v2;  v3 = (v3 > 0.f) ? v3 : 0.01f * v3;
    v4 = (v4 > 0.f) ? v4 : 0.01f * v4;  v5 = (v5 > 0.f) ? v5 : 0.01f * v5;
    v6 = (v6 > 0.f) ? v6 : 0.01f * v6;  v7 = (v7 > 0.f) ? v7 : 0.01f * v7;

    if constexpr (MODE == 0) {
        // stash activated layer-1 row in per-wave LDS
        if (g == 0) {
            float4 w0; w0.x = v0; w0.y = v1; w0.z = v2; w0.w = v3;
            float4 w1; w1.x = v4; w1.y = v5; w1.z = v6; w1.w = v7;
            *(float4*)&xrow[wv][l * 8]     = w0;
            *(float4*)&xrow[wv][l * 8 + 4] = w1;
        }
        __syncthreads();   // also orders vs other waves' Ws usage; uniform

        // layer-2 linear: quarter-wave q handles k in [q*16,(q+1)*16)
        const int q  = ln >> 4;
        const int c4 = (ln & 15) * 4;
        float4 o = {0.f, 0.f, 0.f, 0.f};
#pragma unroll
        for (int kk = 0; kk < 16; ++kk) {
            const int k = q * 16 + kk;
            const float xv = xrow[wv][k];
            const float4 w = *(const float4*)&Ws[k * F + c4];
            o.x = fmaf(xv, w.x, o.x);
            o.y = fmaf(xv, w.y, o.y);
            o.z = fmaf(xv, w.z, o.z);
            o.w = fmaf(xv, w.w, o.w);
        }
        o.x += __shfl_xor(o.x, 16, 64); o.x += __shfl_xor(o.x, 32, 64);
        o.y += __shfl_xor(o.y, 16, 64); o.y += __shfl_xor(o.y, 32, 64);
        o.z += __shfl_xor(o.z, 16, 64); o.z += __shfl_xor(o.z, 32, 64);
        o.w += __shfl_xor(o.w, 16, 64); o.w += __shfl_xor(o.w, 32, 64);

        float vs = o.x * asv[c4] + o.y * asv[c4+1] + o.z * asv[c4+2] + o.w * asv[c4+3];
        float vd = o.x * adv[c4] + o.y * adv[c4+1] + o.z * adv[c4+2] + o.w * adv[c4+3];
#pragma unroll
        for (int off = 1; off < 16; off <<= 1) {
            vs += __shfl_xor(vs, off, 64);
            vd += __shfl_xor(vd, off, 64);
        }
        if (ln == 0) { as_out[node] = vs; ad_out[node] = vd; }
        if (q == 0) {
            uint2 p;
            p.x = f2bf2(o.x, o.y);
            p.y = f2bf2(o.z, o.w);
            *(uint2*)&hout[(size_t)node * F + c4] = p;
        }
    } else {
        if (g == 0) {
            const float4 r0 = *(const float4*)(resid + (size_t)node * F + l * 8);
            const float4 r1 = *(const float4*)(resid + (size_t)node * F + l * 8 + 4);
            float4 o0, o1;
            o0.x = v0 + r0.x; o0.y = v1 + r0.y; o0.z = v2 + r0.z; o0.w = v3 + r0.w;
            o1.x = v4 + r1.x; o1.y = v5 + r1.y; o1.z = v6 + r1.z; o1.w = v7 + r1.w;
            *(float4*)(out + (size_t)node * F + l * 8)     = o0;
            *(float4*)(out + (size_t)node * F + l * 8 + 4) = o1;
        }
    }
}

extern "C" void kernel_launch(void* const* d_in, const int* in_sizes, int n_in,
                              void* d_out, int out_size, void* d_ws, size_t ws_size,
                              hipStream_t stream)
{
    const float* x   = (const float*)d_in[0];
    const int*   ei  = (const int*)  d_in[1];   // [2, NEDGES] row-major
    const float* W0  = (const float*)d_in[2];
    const float* as0 = (const float*)d_in[3];
    const float* ad0 = (const float*)d_in[4];
    const float* b0  = (const float*)d_in[5];
    const float* W1  = (const float*)d_in[6];
    const float* as1 = (const float*)d_in[7];
    const float* ad1 = (const float*)d_in[8];
    const float* b1  = (const float*)d_in[9];
    float* out = (float*)d_out;

    const int* src = ei;
    const int* dst = ei + NEDGES;

    // workspace carve-up (~21 MB)
    char* ws = (char*)d_ws;
    u16*   h16    = (u16*)ws;   ws += (size_t)NNODES * F * 2;   // layer-1 h
    u16*   h2_16  = (u16*)ws;   ws += (size_t)NNODES * F * 2;   // layer-2 h
    float* as_    = (float*)ws; ws += (size_t)NNODES * 4;
    float* ad_    = (float*)ws; ws += (size_t)NNODES * 4;
    float* as2    = (float*)ws; ws += (size_t)NNODES * 4;
    float* ad2    = (float*)ws; ws += (size_t)NNODES * 4;
    int*   rowptr = (int*)ws;   ws += (size_t)NNODES * 4;
    int*   rowcnt = (int*)ws;   ws += (size_t)NNODES * 4;
    int*   gcur   = (int*)ws;   ws += (size_t)NB * 4;
    u32*   stg    = (u32*)ws;   ws += (size_t)NB * CAP * 4;
    u16*   csr    = (u16*)ws;   ws += (size_t)NB * CAP * 2;

    hipMemsetAsync(gcur, 0, (size_t)NB * 4, stream);
    stage_linear1<<<SBLK + LIN_BLOCKS, 256, 0, stream>>>(
        x, W0, as0, ad0, h16, as_, ad_, src, dst, gcur, stg);
    bucket_csr<<<NB, 256, 0, stream>>>(gcur, stg, csr, rowptr, rowcnt);

    // layer-1 aggregate + fused layer-2 linear
    gat_agg<0><<<AGG_BLOCKS, 256, 0, stream>>>(
        rowptr, rowcnt, csr, h16, as_, ad_, b0,
        W1, as1, ad1, h2_16, as2, ad2, nullptr, nullptr);
    // layer-2 aggregate + residual
    gat_agg<1><<<AGG_BLOCKS, 256, 0, stream>>>(
        rowptr, rowcnt, csr, h2_16, as2, ad2, b1,
        nullptr, nullptr, nullptr, nullptr, nullptr, nullptr, x, out);
}

// Round 8
// 171.717 us; speedup vs baseline: 1.3888x; 1.1226x over previous
//
#include <hip/hip_runtime.h>
#include <math.h>

#define NNODES 50000
#define NEDGES 800000
#define ETOT   850000            // edges + self loops
#define F      64
#define NB     782               // ceil(NNODES/64) buckets of 64 nodes
#define CAP    1408              // fixed slots per bucket (max count ~1200)
#define LIN_BLOCKS 3125          // 16 nodes / block
#define AGG_BLOCKS 1563          // ceil(NNODES/32): 32 nodes / block, 8 lanes / node
#define SBLK   256               // staging blocks (1 per CU)
#define SIT    13                // edges/thread in staging
#define SEPB   (256 * SIT)       // 3328 edges per staging block

typedef unsigned short u16;
typedef unsigned int   u32;

// pack two f32 -> two bf16 (RNE)
__device__ __forceinline__ u32 f2bf2(float a, float b) {
    u32 ua = __float_as_uint(a), ub = __float_as_uint(b);
    ua = (ua + 0x7FFFu + ((ua >> 16) & 1u)) >> 16;
    ub = (ub + 0x7FFFu + ((ub >> 16) & 1u)) >> 16;
    return ua | (ub << 16);
}

// shared-memory layout for the linear body (aliased by the stage path)
struct LinSmem {
    float Ws[F * F];        // 16 KB
    float xs[16][F + 1];
    float asv[F], adv[F];
};

// ---------------------------------------------------------------------------
// Linear body: h16 = bf16(x @ W) ; as_ = (xW).a_src ; ad_ = (xW).a_dst
// 16 nodes / block; quarter-wave (16 lanes) per node, 4 output cols per lane.
// ---------------------------------------------------------------------------
__device__ __forceinline__ void linear_body(
    LinSmem& sm,
    const float* __restrict__ x, const float* __restrict__ W,
    const float* __restrict__ a_src, const float* __restrict__ a_dst,
    u16* __restrict__ h16, float* __restrict__ as_, float* __restrict__ ad_,
    int blk)
{
    const int tid = threadIdx.x;
    const int wv  = tid >> 6;
    const int ln  = tid & 63;
    const int q   = ln >> 4;
    const int fl4 = (ln & 15) * 4;
    const int nb  = wv * 4 + q;
    const int node = blk * 16 + nb;

    for (int i = tid * 4; i < F * F; i += 1024)
        *(float4*)&sm.Ws[i] = *(const float4*)&W[i];
    if (tid < F) { sm.asv[tid] = a_src[tid]; sm.adv[tid] = a_dst[tid]; }
    {
        const int n  = tid >> 4;
        const int c4 = (tid & 15) * 4;
        const float4 v = *(const float4*)&x[(size_t)(blk * 16 + n) * F + c4];
        sm.xs[n][c4] = v.x; sm.xs[n][c4+1] = v.y;
        sm.xs[n][c4+2] = v.z; sm.xs[n][c4+3] = v.w;
    }
    __syncthreads();

    float4 acc = {0.f, 0.f, 0.f, 0.f};
#pragma unroll
    for (int k = 0; k < F; ++k) {
        const float xv = sm.xs[nb][k];
        const float4 w = *(const float4*)&sm.Ws[k * F + fl4];
        acc.x = fmaf(xv, w.x, acc.x);
        acc.y = fmaf(xv, w.y, acc.y);
        acc.z = fmaf(xv, w.z, acc.z);
        acc.w = fmaf(xv, w.w, acc.w);
    }

    uint2 p;
    p.x = f2bf2(acc.x, acc.y);
    p.y = f2bf2(acc.z, acc.w);
    *(uint2*)(h16 + (size_t)node * F + fl4) = p;

    float vs = acc.x * sm.asv[fl4] + acc.y * sm.asv[fl4+1]
             + acc.z * sm.asv[fl4+2] + acc.w * sm.asv[fl4+3];
    float vd = acc.x * sm.adv[fl4] + acc.y * sm.adv[fl4+1]
             + acc.z * sm.adv[fl4+2] + acc.w * sm.adv[fl4+3];
#pragma unroll
    for (int off = 1; off < 16; off <<= 1) {
        vs += __shfl_xor(vs, off, 64);
        vd += __shfl_xor(vd, off, 64);
    }
    if ((ln & 15) == 0) { as_[node] = vs; ad_[node] = vd; }
}

// ---------------------------------------------------------------------------
// K1: blocks [0,SBLK): stage edges into fixed-CAP bucket regions.
//     blocks [SBLK..): layer-1 linear (stage latency hides under it).
// ---------------------------------------------------------------------------
__global__ __launch_bounds__(256) void stage_linear1(
    const float* __restrict__ x, const float* __restrict__ W,
    const float* __restrict__ a_src, const float* __restrict__ a_dst,
    u16* __restrict__ h16, float* __restrict__ as_, float* __restrict__ ad_,
    const int* __restrict__ src, const int* __restrict__ dst,
    int* __restrict__ gcur, u32* __restrict__ stg)
{
    __shared__ LinSmem sm;
    if (blockIdx.x < SBLK) {
        int* cnt  = (int*)&sm;          // NB ints
        int* lcur = cnt + NB;           // NB ints
        for (int i = threadIdx.x; i < NB; i += 256) cnt[i] = 0;
        __syncthreads();
        const int base = blockIdx.x * SEPB;
#pragma unroll
        for (int it = 0; it < SIT; ++it) {
            const int e = base + it * 256 + threadIdx.x;
            if (e < ETOT) {
                const int d = (e < NEDGES) ? dst[e] : (e - NEDGES);
                atomicAdd(&cnt[d >> 6], 1);
            }
        }
        __syncthreads();
        for (int i = threadIdx.x; i < NB; i += 256)
            lcur[i] = cnt[i] ? (i * CAP + atomicAdd(&gcur[i], cnt[i])) : 0;
        __syncthreads();
#pragma unroll
        for (int it = 0; it < SIT; ++it) {
            const int e = base + it * 256 + threadIdx.x;
            if (e < ETOT) {
                int s, d;
                if (e < NEDGES) { s = src[e]; d = dst[e]; }
                else            { s = e - NEDGES; d = s; }
                const int p = atomicAdd(&lcur[d >> 6], 1);
                stg[p] = ((u32)(d & 63) << 16) | (u32)s;
            }
        }
        return;
    }
    linear_body(sm, x, W, a_src, a_dst, h16, as_, ad_, blockIdx.x - SBLK);
}

// ---------------------------------------------------------------------------
// K2: per bucket: 64-node histogram, shfl_up scan -> rowptr/rowcnt, scatter
// u16 src ids into per-node csr slots.
// ---------------------------------------------------------------------------
__global__ __launch_bounds__(256) void bucket_csr(
    const int* __restrict__ gcur, const u32* __restrict__ stg,
    u16* __restrict__ csr, int* __restrict__ rowptr, int* __restrict__ rowcnt)
{
    __shared__ int cnt[64];
    const int b = blockIdx.x;
    const int nbase = b << 6;
    const int nr  = (NNODES - nbase < 64) ? (NNODES - nbase) : 64;
    const int beg = b * CAP;
    const int m   = gcur[b];

    if (threadIdx.x < 64) cnt[threadIdx.x] = 0;
    __syncthreads();
    for (int i = threadIdx.x; i < m; i += 256)
        atomicAdd(&cnt[stg[beg + i] >> 16], 1);
    __syncthreads();
    if (threadIdx.x < 64) {
        const int v = cnt[threadIdx.x];
        int incl = v;
#pragma unroll
        for (int off = 1; off < 64; off <<= 1) {
            const int t = __shfl_up(incl, off, 64);
            if (threadIdx.x >= off) incl += t;
        }
        const int pos = beg + incl - v;
        cnt[threadIdx.x] = pos;
        if (threadIdx.x < nr) {
            rowptr[nbase + threadIdx.x] = pos;
            rowcnt[nbase + threadIdx.x] = v;
        }
    }
    __syncthreads();
    for (int i = threadIdx.x; i < m; i += 256) {
        const u32 pk = stg[beg + i];
        const int pos = atomicAdd(&cnt[pk >> 16], 1);
        csr[pos] = (u16)(pk & 0xFFFFu);
    }
}

// ---------------------------------------------------------------------------
// K3/K4: softmax + aggregate + bias + LeakyReLU(0.01).
// 8 lanes per NODE (lane l owns features l*8..l*8+7), 8 nodes per wave,
// 32 nodes per block. Accumulator IS the output row slice: no cross-lane
// reduce, no per-node wave prologue. z computed redundantly per lane.
// MODE 0 epilogue: fused layer-2 linear (xs LDS, per-thread 8 cols).
// MODE 1 epilogue: + residual, f32 out.
// ---------------------------------------------------------------------------
#define XSP 68   // xs row pad (floats): conflict-free broadcast + aligned f4
template<int MODE>
__global__ __launch_bounds__(256) void gat_agg(
    const int* __restrict__ rowptr, const int* __restrict__ rowcnt,
    const u16* __restrict__ csr, const u16* __restrict__ hin,
    const float* __restrict__ as_, const float* __restrict__ ad_,
    const float* __restrict__ bias,
    const float* __restrict__ Wn, const float* __restrict__ an_s,
    const float* __restrict__ an_d,
    u16* __restrict__ hout, float* __restrict__ as_out, float* __restrict__ ad_out,
    const float* __restrict__ resid, float* __restrict__ out)
{
    __shared__ float Ws[MODE == 0 ? F * F : 1];
    __shared__ float asv[MODE == 0 ? F : 1], adv[MODE == 0 ? F : 1];
    __shared__ float xs[MODE == 0 ? 32 * XSP : 1];

    const int tid = threadIdx.x;
    const int ln  = tid & 63;
    const int g   = ln >> 3;               // node group within wave
    const int l   = ln & 7;                // 16B chunk of the 128B bf16 row
    const int nb  = (tid >> 6) * 8 + g;    // node within block (0..31)
    const int node = blockIdx.x * 32 + nb;
    const bool valid = node < NNODES;

    if constexpr (MODE == 0) {
        for (int i = tid * 4; i < F * F; i += 1024)
            *(float4*)&Ws[i] = *(const float4*)&Wn[i];
        if (tid < F) { asv[tid] = an_s[tid]; adv[tid] = an_d[tid]; }
    }

    int beg = 0, cnt = 0;
    float ad_n = 0.f;
    if (valid) {
        beg  = rowptr[node];
        cnt  = rowcnt[node];
        ad_n = ad_[node];
    }

    float a0=0.f,a1=0.f,a2=0.f,a3=0.f,a4=0.f,a5=0.f,a6=0.f,a7=0.f;
    float z = 0.f;
    int i = 0;
    for (; i + 1 < cnt; i += 2) {          // 2 edges in flight per node
        const int s1 = csr[beg + i];
        const int s2 = csr[beg + i + 1];
        const float r1 = as_[s1] + ad_n;
        const float r2 = as_[s2] + ad_n;
        const uint4 h1 = ((const uint4*)(hin + (size_t)s1 * F))[l];
        const uint4 h2 = ((const uint4*)(hin + (size_t)s2 * F))[l];
        const float t1 = (r1 > 0.f) ? r1 : 0.2f * r1;
        const float t2 = (r2 > 0.f) ? r2 : 0.2f * r2;
        const float e1 = __expf(t1);
        const float e2 = __expf(t2);
        z += e1 + e2;
        a0 = fmaf(e1, __uint_as_float(h1.x << 16),         a0);
        a1 = fmaf(e1, __uint_as_float(h1.x & 0xFFFF0000u), a1);
        a2 = fmaf(e1, __uint_as_float(h1.y << 16),         a2);
        a3 = fmaf(e1, __uint_as_float(h1.y & 0xFFFF0000u), a3);
        a4 = fmaf(e1, __uint_as_float(h1.z << 16),         a4);
        a5 = fmaf(e1, __uint_as_float(h1.z & 0xFFFF0000u), a5);
        a6 = fmaf(e1, __uint_as_float(h1.w << 16),         a6);
        a7 = fmaf(e1, __uint_as_float(h1.w & 0xFFFF0000u), a7);
        a0 = fmaf(e2, __uint_as_float(h2.x << 16),         a0);
        a1 = fmaf(e2, __uint_as_float(h2.x & 0xFFFF0000u), a1);
        a2 = fmaf(e2, __uint_as_float(h2.y << 16),         a2);
        a3 = fmaf(e2, __uint_as_float(h2.y & 0xFFFF0000u), a3);
        a4 = fmaf(e2, __uint_as_float(h2.z << 16),         a4);
        a5 = fmaf(e2, __uint_as_float(h2.z & 0xFFFF0000u), a5);
        a6 = fmaf(e2, __uint_as_float(h2.w << 16),         a6);
        a7 = fmaf(e2, __uint_as_float(h2.w & 0xFFFF0000u), a7);
    }
    if (i < cnt) {                          // odd-degree tail
        const int s1 = csr[beg + i];
        const float r1 = as_[s1] + ad_n;
        const uint4 h1 = ((const uint4*)(hin + (size_t)s1 * F))[l];
        const float t1 = (r1 > 0.f) ? r1 : 0.2f * r1;
        const float e1 = __expf(t1);
        z += e1;
        a0 = fmaf(e1, __uint_as_float(h1.x << 16),         a0);
        a1 = fmaf(e1, __uint_as_float(h1.x & 0xFFFF0000u), a1);
        a2 = fmaf(e1, __uint_as_float(h1.y << 16),         a2);
        a3 = fmaf(e1, __uint_as_float(h1.y & 0xFFFF0000u), a3);
        a4 = fmaf(e1, __uint_as_float(h1.z << 16),         a4);
        a5 = fmaf(e1, __uint_as_float(h1.z & 0xFFFF0000u), a5);
        a6 = fmaf(e1, __uint_as_float(h1.w << 16),         a6);
        a7 = fmaf(e1, __uint_as_float(h1.w & 0xFFFF0000u), a7);
    }

    const float inv = 1.f / (z + 1e-16f);
    const float4 b0v = *(const float4*)&bias[l * 8];
    const float4 b1v = *(const float4*)&bias[l * 8 + 4];
    float v0 = a0 * inv + b0v.x, v1 = a1 * inv + b0v.y;
    float v2 = a2 * inv + b0v.z, v3 = a3 * inv + b0v.w;
    float v4 = a4 * inv + b1v.x, v5 = a5 * inv + b1v.y;
    float v6 = a6 * inv + b1v.z, v7 = a7 * inv + b1v.w;
    v0 = (v0 > 0.f) ? v0 : 0.01f * v0;  v1 = (v1 > 0.f) ? v1 : 0.01f * v1;
    v2 = (v2 > 0.f) ? v2 : 0.01f * v2;  v3 = (v3 > 0.f) ? v3 : 0.01f * v3;
    v4 = (v4 > 0.f) ? v4 : 0.01f * v4;  v5 = (v5 > 0.f) ? v5 : 0.01f * v5;
    v6 = (v6 > 0.f) ? v6 : 0.01f * v6;  v7 = (v7 > 0.f) ? v7 : 0.01f * v7;

    if constexpr (MODE == 0) {
        // stash activated layer-1 rows, then per-thread layer-2 GEMM
        {
            float4 w0; w0.x = v0; w0.y = v1; w0.z = v2; w0.w = v3;
            float4 w1; w1.x = v4; w1.y = v5; w1.z = v6; w1.w = v7;
            const int xb = nb * XSP + l * 8;
            *(float4*)&xs[xb]     = w0;
            *(float4*)&xs[xb + 4] = w1;
        }
        __syncthreads();

        const int nb2 = tid >> 3;          // node 0..31
        const int c0  = (tid & 7) * 8;     // 8 output cols
        float o0=0.f,o1=0.f,o2=0.f,o3=0.f,o4=0.f,o5=0.f,o6=0.f,o7=0.f;
#pragma unroll 8
        for (int k = 0; k < F; ++k) {
            const float xv = xs[nb2 * XSP + k];
            const float4 wa = *(const float4*)&Ws[k * F + c0];
            const float4 wb = *(const float4*)&Ws[k * F + c0 + 4];
            o0 = fmaf(xv, wa.x, o0); o1 = fmaf(xv, wa.y, o1);
            o2 = fmaf(xv, wa.z, o2); o3 = fmaf(xv, wa.w, o3);
            o4 = fmaf(xv, wb.x, o4); o5 = fmaf(xv, wb.y, o5);
            o6 = fmaf(xv, wb.z, o6); o7 = fmaf(xv, wb.w, o7);
        }
        const int node2 = blockIdx.x * 32 + nb2;
        float vs = o0*asv[c0]   + o1*asv[c0+1] + o2*asv[c0+2] + o3*asv[c0+3]
                 + o4*asv[c0+4] + o5*asv[c0+5] + o6*asv[c0+6] + o7*asv[c0+7];
        float vd = o0*adv[c0]   + o1*adv[c0+1] + o2*adv[c0+2] + o3*adv[c0+3]
                 + o4*adv[c0+4] + o5*adv[c0+5] + o6*adv[c0+6] + o7*adv[c0+7];
        vs += __shfl_xor(vs, 1, 64); vs += __shfl_xor(vs, 2, 64); vs += __shfl_xor(vs, 4, 64);
        vd += __shfl_xor(vd, 1, 64); vd += __shfl_xor(vd, 2, 64); vd += __shfl_xor(vd, 4, 64);
        if (node2 < NNODES) {
            if ((tid & 7) == 0) { as_out[node2] = vs; ad_out[node2] = vd; }
            uint4 p;
            p.x = f2bf2(o0, o1); p.y = f2bf2(o2, o3);
            p.z = f2bf2(o4, o5); p.w = f2bf2(o6, o7);
            *(uint4*)&hout[(size_t)node2 * F + c0] = p;
        }
    } else {
        if (valid) {
            const float4 r0 = *(const float4*)(resid + (size_t)node * F + l * 8);
            const float4 r1 = *(const float4*)(resid + (size_t)node * F + l * 8 + 4);
            float4 o0, o1;
            o0.x = v0 + r0.x; o0.y = v1 + r0.y; o0.z = v2 + r0.z; o0.w = v3 + r0.w;
            o1.x = v4 + r1.x; o1.y = v5 + r1.y; o1.z = v6 + r1.z; o1.w = v7 + r1.w;
            *(float4*)(out + (size_t)node * F + l * 8)     = o0;
            *(float4*)(out + (size_t)node * F + l * 8 + 4) = o1;
        }
    }
}

extern "C" void kernel_launch(void* const* d_in, const int* in_sizes, int n_in,
                              void* d_out, int out_size, void* d_ws, size_t ws_size,
                              hipStream_t stream)
{
    const float* x   = (const float*)d_in[0];
    const int*   ei  = (const int*)  d_in[1];   // [2, NEDGES] row-major
    const float* W0  = (const float*)d_in[2];
    const float* as0 = (const float*)d_in[3];
    const float* ad0 = (const float*)d_in[4];
    const float* b0  = (const float*)d_in[5];
    const float* W1  = (const float*)d_in[6];
    const float* as1 = (const float*)d_in[7];
    const float* ad1 = (const float*)d_in[8];
    const float* b1  = (const float*)d_in[9];
    float* out = (float*)d_out;

    const int* src = ei;
    const int* dst = ei + NEDGES;

    // workspace carve-up (~21 MB)
    char* ws = (char*)d_ws;
    u16*   h16    = (u16*)ws;   ws += (size_t)NNODES * F * 2;   // layer-1 h
    u16*   h2_16  = (u16*)ws;   ws += (size_t)NNODES * F * 2;   // layer-2 h
    float* as_    = (float*)ws; ws += (size_t)NNODES * 4;
    float* ad_    = (float*)ws; ws += (size_t)NNODES * 4;
    float* as2    = (float*)ws; ws += (size_t)NNODES * 4;
    float* ad2    = (float*)ws; ws += (size_t)NNODES * 4;
    int*   rowptr = (int*)ws;   ws += (size_t)NNODES * 4;
    int*   rowcnt = (int*)ws;   ws += (size_t)NNODES * 4;
    int*   gcur   = (int*)ws;   ws += (size_t)NB * 4;
    u32*   stg    = (u32*)ws;   ws += (size_t)NB * CAP * 4;
    u16*   csr    = (u16*)ws;   ws += (size_t)NB * CAP * 2;

    hipMemsetAsync(gcur, 0, (size_t)NB * 4, stream);
    stage_linear1<<<SBLK + LIN_BLOCKS, 256, 0, stream>>>(
        x, W0, as0, ad0, h16, as_, ad_, src, dst, gcur, stg);
    bucket_csr<<<NB, 256, 0, stream>>>(gcur, stg, csr, rowptr, rowcnt);

    // layer-1 aggregate + fused layer-2 linear
    gat_agg<0><<<AGG_BLOCKS, 256, 0, stream>>>(
        rowptr, rowcnt, csr, h16, as_, ad_, b0,
        W1, as1, ad1, h2_16, as2, ad2, nullptr, nullptr);
    // layer-2 aggregate + residual
    gat_agg<1><<<AGG_BLOCKS, 256, 0, stream>>>(
        rowptr, rowcnt, csr, h2_16, as2, ad2, b1,
        nullptr, nullptr, nullptr, nullptr, nullptr, nullptr, x, out);
}

// Round 9
// 170.425 us; speedup vs baseline: 1.3993x; 1.0076x over previous
//
#include <hip/hip_runtime.h>
#include <math.h>

#define NNODES 50000
#define NEDGES 800000
#define ETOT   850000            // edges + self loops
#define F      64
#define NB     782               // ceil(NNODES/64) buckets of 64 nodes
#define CAP    1408              // fixed slots per bucket (max count ~1200)
#define LIN_BLOCKS 1563          // 32 nodes / block
#define AGG_BLOCKS 1563          // 32 nodes / block, 8 lanes / node
#define SBLK   256               // staging blocks (1 per CU)
#define SIT    13                // edges/thread in staging
#define SEPB   (256 * SIT)       // 3328 edges per staging block
#define XSP    68                // padded LDS row stride (floats)

typedef unsigned short u16;
typedef unsigned int   u32;

// pack two f32 -> two bf16 (RNE)
__device__ __forceinline__ u32 f2bf2(float a, float b) {
    u32 ua = __float_as_uint(a), ub = __float_as_uint(b);
    ua = (ua + 0x7FFFu + ((ua >> 16) & 1u)) >> 16;
    ub = (ub + 0x7FFFu + ((ub >> 16) & 1u)) >> 16;
    return ua | (ub << 16);
}

#define ACC8(ev, hv) \
    a0 = fmaf(ev, __uint_as_float(hv.x << 16),         a0); \
    a1 = fmaf(ev, __uint_as_float(hv.x & 0xFFFF0000u), a1); \
    a2 = fmaf(ev, __uint_as_float(hv.y << 16),         a2); \
    a3 = fmaf(ev, __uint_as_float(hv.y & 0xFFFF0000u), a3); \
    a4 = fmaf(ev, __uint_as_float(hv.z << 16),         a4); \
    a5 = fmaf(ev, __uint_as_float(hv.z & 0xFFFF0000u), a5); \
    a6 = fmaf(ev, __uint_as_float(hv.w << 16),         a6); \
    a7 = fmaf(ev, __uint_as_float(hv.w & 0xFFFF0000u), a7)

// shared-memory layout for the linear body (aliased by the stage path)
struct LinSmem {
    float Ws[F * F];          // 16 KB
    float xs[32 * XSP];       // 8.7 KB
    float asv[F], adv[F];
};

// ---------------------------------------------------------------------------
// Linear body: h16 = bf16(x @ W) ; as_ = (xW).a_src ; ad_ = (xW).a_dst
// 32 nodes / block; 8 lanes per node, 8 output cols per lane (same shape as
// the gat_agg<0> epilogue GEMM).
// ---------------------------------------------------------------------------
__device__ __forceinline__ void linear_body(
    LinSmem& sm,
    const float* __restrict__ x, const float* __restrict__ W,
    const float* __restrict__ a_src, const float* __restrict__ a_dst,
    u16* __restrict__ h16, float* __restrict__ as_, float* __restrict__ ad_,
    int blk)
{
    const int tid = threadIdx.x;
    const int n   = tid >> 3;          // node within block 0..31
    const int c0  = (tid & 7) * 8;     // output col base
    const int node = blk * 32 + n;
    const bool valid = node < NNODES;

    for (int i = tid * 4; i < F * F; i += 1024)
        *(float4*)&sm.Ws[i] = *(const float4*)&W[i];
    if (tid < F) { sm.asv[tid] = a_src[tid]; sm.adv[tid] = a_dst[tid]; }
    if (valid) {
        const float4 v0 = *(const float4*)&x[(size_t)node * F + c0];
        const float4 v1 = *(const float4*)&x[(size_t)node * F + c0 + 4];
        *(float4*)&sm.xs[n * XSP + c0]     = v0;
        *(float4*)&sm.xs[n * XSP + c0 + 4] = v1;
    }
    __syncthreads();

    float o0=0.f,o1=0.f,o2=0.f,o3=0.f,o4=0.f,o5=0.f,o6=0.f,o7=0.f;
#pragma unroll 8
    for (int k = 0; k < F; ++k) {
        const float xv = sm.xs[n * XSP + k];
        const float4 wa = *(const float4*)&sm.Ws[k * F + c0];
        const float4 wb = *(const float4*)&sm.Ws[k * F + c0 + 4];
        o0 = fmaf(xv, wa.x, o0); o1 = fmaf(xv, wa.y, o1);
        o2 = fmaf(xv, wa.z, o2); o3 = fmaf(xv, wa.w, o3);
        o4 = fmaf(xv, wb.x, o4); o5 = fmaf(xv, wb.y, o5);
        o6 = fmaf(xv, wb.z, o6); o7 = fmaf(xv, wb.w, o7);
    }

    float vs = o0*sm.asv[c0]   + o1*sm.asv[c0+1] + o2*sm.asv[c0+2] + o3*sm.asv[c0+3]
             + o4*sm.asv[c0+4] + o5*sm.asv[c0+5] + o6*sm.asv[c0+6] + o7*sm.asv[c0+7];
    float vd = o0*sm.adv[c0]   + o1*sm.adv[c0+1] + o2*sm.adv[c0+2] + o3*sm.adv[c0+3]
             + o4*sm.adv[c0+4] + o5*sm.adv[c0+5] + o6*sm.adv[c0+6] + o7*sm.adv[c0+7];
    vs += __shfl_xor(vs, 1, 64); vs += __shfl_xor(vs, 2, 64); vs += __shfl_xor(vs, 4, 64);
    vd += __shfl_xor(vd, 1, 64); vd += __shfl_xor(vd, 2, 64); vd += __shfl_xor(vd, 4, 64);

    if (valid) {
        if ((tid & 7) == 0) { as_[node] = vs; ad_[node] = vd; }
        uint4 p;
        p.x = f2bf2(o0, o1); p.y = f2bf2(o2, o3);
        p.z = f2bf2(o4, o5); p.w = f2bf2(o6, o7);
        *(uint4*)&h16[(size_t)node * F + c0] = p;
    }
}

// ---------------------------------------------------------------------------
// K1: blocks [0,SBLK): stage edges into fixed-CAP bucket regions.
//     Single pass over edge_index: (src,dst) held in registers across the
//     count / reserve / scatter phases.
//     blocks [SBLK..): layer-1 linear (stage latency hides under it).
// ---------------------------------------------------------------------------
__global__ __launch_bounds__(256) void stage_linear1(
    const float* __restrict__ x, const float* __restrict__ W,
    const float* __restrict__ a_src, const float* __restrict__ a_dst,
    u16* __restrict__ h16, float* __restrict__ as_, float* __restrict__ ad_,
    const int* __restrict__ src, const int* __restrict__ dst,
    int* __restrict__ gcur, u32* __restrict__ stg)
{
    __shared__ LinSmem sm;
    if (blockIdx.x < SBLK) {
        int* cnt  = (int*)&sm;          // NB ints
        int* lcur = cnt + NB;           // NB ints (6.3 KB total, aliases sm)
        for (int i = threadIdx.x; i < NB; i += 256) cnt[i] = 0;
        __syncthreads();
        const int base = blockIdx.x * SEPB;
        int es[SIT], ed[SIT];
#pragma unroll
        for (int it = 0; it < SIT; ++it) {
            const int e = base + it * 256 + threadIdx.x;
            if (e < ETOT) {
                int s, d;
                if (e < NEDGES) { s = src[e]; d = dst[e]; }
                else            { s = e - NEDGES; d = s; }
                es[it] = s; ed[it] = d;
                atomicAdd(&cnt[d >> 6], 1);
            } else {
                ed[it] = -1; es[it] = 0;
            }
        }
        __syncthreads();
        for (int i = threadIdx.x; i < NB; i += 256)
            lcur[i] = cnt[i] ? (i * CAP + atomicAdd(&gcur[i], cnt[i])) : 0;
        __syncthreads();
#pragma unroll
        for (int it = 0; it < SIT; ++it) {
            if (ed[it] >= 0) {
                const int p = atomicAdd(&lcur[ed[it] >> 6], 1);
                stg[p] = ((u32)(ed[it] & 63) << 16) | (u32)es[it];
            }
        }
        return;
    }
    linear_body(sm, x, W, a_src, a_dst, h16, as_, ad_, blockIdx.x - SBLK);
}

// ---------------------------------------------------------------------------
// K2: per bucket: 64-node histogram, shfl_up scan -> rowptr/rowcnt, scatter
// u16 src ids into per-node csr slots.
// ---------------------------------------------------------------------------
__global__ __launch_bounds__(256) void bucket_csr(
    const int* __restrict__ gcur, const u32* __restrict__ stg,
    u16* __restrict__ csr, int* __restrict__ rowptr, int* __restrict__ rowcnt)
{
    __shared__ int cnt[64];
    const int b = blockIdx.x;
    const int nbase = b << 6;
    const int nr  = (NNODES - nbase < 64) ? (NNODES - nbase) : 64;
    const int beg = b * CAP;
    const int m   = gcur[b];

    if (threadIdx.x < 64) cnt[threadIdx.x] = 0;
    __syncthreads();
    for (int i = threadIdx.x; i < m; i += 256)
        atomicAdd(&cnt[stg[beg + i] >> 16], 1);
    __syncthreads();
    if (threadIdx.x < 64) {
        const int v = cnt[threadIdx.x];
        int incl = v;
#pragma unroll
        for (int off = 1; off < 64; off <<= 1) {
            const int t = __shfl_up(incl, off, 64);
            if (threadIdx.x >= off) incl += t;
        }
        const int pos = beg + incl - v;
        cnt[threadIdx.x] = pos;
        if (threadIdx.x < nr) {
            rowptr[nbase + threadIdx.x] = pos;
            rowcnt[nbase + threadIdx.x] = v;
        }
    }
    __syncthreads();
    for (int i = threadIdx.x; i < m; i += 256) {
        const u32 pk = stg[beg + i];
        const int pos = atomicAdd(&cnt[pk >> 16], 1);
        csr[pos] = (u16)(pk & 0xFFFFu);
    }
}

// ---------------------------------------------------------------------------
// K3/K4: softmax + aggregate + bias + LeakyReLU(0.01).
// 8 lanes per NODE (lane l owns features l*8..l*8+7), 8 nodes per wave,
// 32 nodes per block. 4 edges in flight per node (unroll x4, masked tail).
// MODE 0 epilogue: fused layer-2 linear. MODE 1 epilogue: +residual, f32 out.
// ---------------------------------------------------------------------------
template<int MODE>
__global__ __launch_bounds__(256) void gat_agg(
    const int* __restrict__ rowptr, const int* __restrict__ rowcnt,
    const u16* __restrict__ csr, const u16* __restrict__ hin,
    const float* __restrict__ as_, const float* __restrict__ ad_,
    const float* __restrict__ bias,
    const float* __restrict__ Wn, const float* __restrict__ an_s,
    const float* __restrict__ an_d,
    u16* __restrict__ hout, float* __restrict__ as_out, float* __restrict__ ad_out,
    const float* __restrict__ resid, float* __restrict__ out)
{
    __shared__ float Ws[MODE == 0 ? F * F : 1];
    __shared__ float asv[MODE == 0 ? F : 1], adv[MODE == 0 ? F : 1];
    __shared__ float xs[MODE == 0 ? 32 * XSP : 1];

    const int tid = threadIdx.x;
    const int ln  = tid & 63;
    const int g   = ln >> 3;               // node group within wave
    const int l   = ln & 7;                // 16B chunk of the 128B bf16 row
    const int nb  = (tid >> 6) * 8 + g;    // node within block (0..31)
    const int node = blockIdx.x * 32 + nb;
    const bool valid = node < NNODES;

    if constexpr (MODE == 0) {
        for (int i = tid * 4; i < F * F; i += 1024)
            *(float4*)&Ws[i] = *(const float4*)&Wn[i];
        if (tid < F) { asv[tid] = an_s[tid]; adv[tid] = an_d[tid]; }
    }

    int beg = 0, cnt = 0;
    float ad_n = 0.f;
    if (valid) {
        beg  = rowptr[node];
        cnt  = rowcnt[node];
        ad_n = ad_[node];
    }

    float a0=0.f,a1=0.f,a2=0.f,a3=0.f,a4=0.f,a5=0.f,a6=0.f,a7=0.f;
    float z = 0.f;
    const int nfull = cnt & ~3;
    int i = 0;
    for (; i < nfull; i += 4) {            // 4 edges in flight per node
        const int s1 = csr[beg + i];
        const int s2 = csr[beg + i + 1];
        const int s3 = csr[beg + i + 2];
        const int s4 = csr[beg + i + 3];
        const float r1 = as_[s1] + ad_n;
        const float r2 = as_[s2] + ad_n;
        const float r3 = as_[s3] + ad_n;
        const float r4 = as_[s4] + ad_n;
        const uint4 h1 = ((const uint4*)(hin + (size_t)s1 * F))[l];
        const uint4 h2 = ((const uint4*)(hin + (size_t)s2 * F))[l];
        const uint4 h3 = ((const uint4*)(hin + (size_t)s3 * F))[l];
        const uint4 h4 = ((const uint4*)(hin + (size_t)s4 * F))[l];
        const float t1 = (r1 > 0.f) ? r1 : 0.2f * r1;
        const float t2 = (r2 > 0.f) ? r2 : 0.2f * r2;
        const float t3 = (r3 > 0.f) ? r3 : 0.2f * r3;
        const float t4 = (r4 > 0.f) ? r4 : 0.2f * r4;
        const float e1 = __expf(t1);
        const float e2 = __expf(t2);
        const float e3 = __expf(t3);
        const float e4 = __expf(t4);
        z += (e1 + e2) + (e3 + e4);
        ACC8(e1, h1); ACC8(e2, h2); ACC8(e3, h3); ACC8(e4, h4);
    }
    if (i < cnt) {                          // masked-parallel tail (1..3 edges)
        const int j2 = (i + 1 < cnt) ? (i + 1) : i;
        const int j3 = (i + 2 < cnt) ? (i + 2) : i;
        const int s1 = csr[beg + i];
        const int s2 = csr[beg + j2];
        const int s3 = csr[beg + j3];
        const float r1 = as_[s1] + ad_n;
        const float r2 = as_[s2] + ad_n;
        const float r3 = as_[s3] + ad_n;
        const uint4 h1 = ((const uint4*)(hin + (size_t)s1 * F))[l];
        const uint4 h2 = ((const uint4*)(hin + (size_t)s2 * F))[l];
        const uint4 h3 = ((const uint4*)(hin + (size_t)s3 * F))[l];
        const float t1 = (r1 > 0.f) ? r1 : 0.2f * r1;
        const float t2 = (r2 > 0.f) ? r2 : 0.2f * r2;
        const float t3 = (r3 > 0.f) ? r3 : 0.2f * r3;
        const float e1 = __expf(t1);
        const float e2 = (i + 1 < cnt) ? __expf(t2) : 0.f;
        const float e3 = (i + 2 < cnt) ? __expf(t3) : 0.f;
        z += e1 + e2 + e3;
        ACC8(e1, h1); ACC8(e2, h2); ACC8(e3, h3);
    }

    const float inv = 1.f / (z + 1e-16f);
    const float4 b0v = *(const float4*)&bias[l * 8];
    const float4 b1v = *(const float4*)&bias[l * 8 + 4];
    float v0 = a0 * inv + b0v.x, v1 = a1 * inv + b0v.y;
    float v2 = a2 * inv + b0v.z, v3 = a3 * inv + b0v.w;
    float v4 = a4 * inv + b1v.x, v5 = a5 * inv + b1v.y;
    float v6 = a6 * inv + b1v.z, v7 = a7 * inv + b1v.w;
    v0 = (v0 > 0.f) ? v0 : 0.01f * v0;  v1 = (v1 > 0.f) ? v1 : 0.01f * v1;
    v2 = (v2 > 0.f) ? v2 : 0.01f * v2;  v3 = (v3 > 0.f) ? v3 : 0.01f * v3;
    v4 = (v4 > 0.f) ? v4 : 0.01f * v4;  v5 = (v5 > 0.f) ? v5 : 0.01f * v5;
    v6 = (v6 > 0.f) ? v6 : 0.01f * v6;  v7 = (v7 > 0.f) ? v7 : 0.01f * v7;

    if constexpr (MODE == 0) {
        // stash activated layer-1 rows, then per-thread layer-2 GEMM
        {
            float4 w0; w0.x = v0; w0.y = v1; w0.z = v2; w0.w = v3;
            float4 w1; w1.x = v4; w1.y = v5; w1.z = v6; w1.w = v7;
            const int xb = nb * XSP + l * 8;
            *(float4*)&xs[xb]     = w0;
            *(float4*)&xs[xb + 4] = w1;
        }
        __syncthreads();

        const int nb2 = tid >> 3;          // node 0..31
        const int c0  = (tid & 7) * 8;     // 8 output cols
        float o0=0.f,o1=0.f,o2=0.f,o3=0.f,o4=0.f,o5=0.f,o6=0.f,o7=0.f;
#pragma unroll 8
        for (int k = 0; k < F; ++k) {
            const float xv = xs[nb2 * XSP + k];
            const float4 wa = *(const float4*)&Ws[k * F + c0];
            const float4 wb = *(const float4*)&Ws[k * F + c0 + 4];
            o0 = fmaf(xv, wa.x, o0); o1 = fmaf(xv, wa.y, o1);
            o2 = fmaf(xv, wa.z, o2); o3 = fmaf(xv, wa.w, o3);
            o4 = fmaf(xv, wb.x, o4); o5 = fmaf(xv, wb.y, o5);
            o6 = fmaf(xv, wb.z, o6); o7 = fmaf(xv, wb.w, o7);
        }
        const int node2 = blockIdx.x * 32 + nb2;
        float vs = o0*asv[c0]   + o1*asv[c0+1] + o2*asv[c0+2] + o3*asv[c0+3]
                 + o4*asv[c0+4] + o5*asv[c0+5] + o6*asv[c0+6] + o7*asv[c0+7];
        float vd = o0*adv[c0]   + o1*adv[c0+1] + o2*adv[c0+2] + o3*adv[c0+3]
                 + o4*adv[c0+4] + o5*adv[c0+5] + o6*adv[c0+6] + o7*adv[c0+7];
        vs += __shfl_xor(vs, 1, 64); vs += __shfl_xor(vs, 2, 64); vs += __shfl_xor(vs, 4, 64);
        vd += __shfl_xor(vd, 1, 64); vd += __shfl_xor(vd, 2, 64); vd += __shfl_xor(vd, 4, 64);
        if (node2 < NNODES) {
            if ((tid & 7) == 0) { as_out[node2] = vs; ad_out[node2] = vd; }
            uint4 p;
            p.x = f2bf2(o0, o1); p.y = f2bf2(o2, o3);
            p.z = f2bf2(o4, o5); p.w = f2bf2(o6, o7);
            *(uint4*)&hout[(size_t)node2 * F + c0] = p;
        }
    } else {
        if (valid) {
            const float4 r0 = *(const float4*)(resid + (size_t)node * F + l * 8);
            const float4 r1 = *(const float4*)(resid + (size_t)node * F + l * 8 + 4);
            float4 o0, o1;
            o0.x = v0 + r0.x; o0.y = v1 + r0.y; o0.z = v2 + r0.z; o0.w = v3 + r0.w;
            o1.x = v4 + r1.x; o1.y = v5 + r1.y; o1.z = v6 + r1.z; o1.w = v7 + r1.w;
            *(float4*)(out + (size_t)node * F + l * 8)     = o0;
            *(float4*)(out + (size_t)node * F + l * 8 + 4) = o1;
        }
    }
}

extern "C" void kernel_launch(void* const* d_in, const int* in_sizes, int n_in,
                              void* d_out, int out_size, void* d_ws, size_t ws_size,
                              hipStream_t stream)
{
    const float* x   = (const float*)d_in[0];
    const int*   ei  = (const int*)  d_in[1];   // [2, NEDGES] row-major
    const float* W0  = (const float*)d_in[2];
    const float* as0 = (const float*)d_in[3];
    const float* ad0 = (const float*)d_in[4];
    const float* b0  = (const float*)d_in[5];
    const float* W1  = (const float*)d_in[6];
    const float* as1 = (const float*)d_in[7];
    const float* ad1 = (const float*)d_in[8];
    const float* b1  = (const float*)d_in[9];
    float* out = (float*)d_out;

    const int* src = ei;
    const int* dst = ei + NEDGES;

    // workspace carve-up (~21 MB)
    char* ws = (char*)d_ws;
    u16*   h16    = (u16*)ws;   ws += (size_t)NNODES * F * 2;   // layer-1 h
    u16*   h2_16  = (u16*)ws;   ws += (size_t)NNODES * F * 2;   // layer-2 h
    float* as_    = (float*)ws; ws += (size_t)NNODES * 4;
    float* ad_    = (float*)ws; ws += (size_t)NNODES * 4;
    float* as2    = (float*)ws; ws += (size_t)NNODES * 4;
    float* ad2    = (float*)ws; ws += (size_t)NNODES * 4;
    int*   rowptr = (int*)ws;   ws += (size_t)NNODES * 4;
    int*   rowcnt = (int*)ws;   ws += (size_t)NNODES * 4;
    int*   gcur   = (int*)ws;   ws += (size_t)NB * 4;
    u32*   stg    = (u32*)ws;   ws += (size_t)NB * CAP * 4;
    u16*   csr    = (u16*)ws;   ws += (size_t)NB * CAP * 2;

    hipMemsetAsync(gcur, 0, (size_t)NB * 4, stream);
    stage_linear1<<<SBLK + LIN_BLOCKS, 256, 0, stream>>>(
        x, W0, as0, ad0, h16, as_, ad_, src, dst, gcur, stg);
    bucket_csr<<<NB, 256, 0, stream>>>(gcur, stg, csr, rowptr, rowcnt);

    // layer-1 aggregate + fused layer-2 linear
    gat_agg<0><<<AGG_BLOCKS, 256, 0, stream>>>(
        rowptr, rowcnt, csr, h16, as_, ad_, b0,
        W1, as1, ad1, h2_16, as2, ad2, nullptr, nullptr);
    // layer-2 aggregate + residual
    gat_agg<1><<<AGG_BLOCKS, 256, 0, stream>>>(
        rowptr, rowcnt, csr, h2_16, as2, ad2, b1,
        nullptr, nullptr, nullptr, nullptr, nullptr, nullptr, x, out);
}

// Round 10
// 166.597 us; speedup vs baseline: 1.4315x; 1.0230x over previous
//
#include <hip/hip_runtime.h>
#include <hip/hip_fp16.h>
#include <math.h>

#define NNODES 50000
#define NEDGES 800000
#define ETOT   850000            // edges + self loops
#define F      64
#define NB     782               // ceil(NNODES/64) buckets of 64 nodes
#define CAP    1408              // fixed slots per bucket (max count ~1200)
#define LIN_BLOCKS 1563          // 32 nodes / block
#define SBLK   256               // staging blocks (1 per CU)
#define SIT    13                // edges/thread in staging
#define SEPB   (256 * SIT)       // 3328 edges per staging block
#define XSP    68                // padded LDS row stride (floats)

typedef unsigned short u16;
typedef unsigned int   u32;

// pack two f32 -> two bf16 (RNE)
__device__ __forceinline__ u32 f2bf2(float a, float b) {
    u32 ua = __float_as_uint(a), ub = __float_as_uint(b);
    ua = (ua + 0x7FFFu + ((ua >> 16) & 1u)) >> 16;
    ub = (ub + 0x7FFFu + ((ub >> 16) & 1u)) >> 16;
    return ua | (ub << 16);
}

#define ACC8(ev, hv) \
    a0 = fmaf(ev, __uint_as_float(hv.x << 16),         a0); \
    a1 = fmaf(ev, __uint_as_float(hv.x & 0xFFFF0000u), a1); \
    a2 = fmaf(ev, __uint_as_float(hv.y << 16),         a2); \
    a3 = fmaf(ev, __uint_as_float(hv.y & 0xFFFF0000u), a3); \
    a4 = fmaf(ev, __uint_as_float(hv.z << 16),         a4); \
    a5 = fmaf(ev, __uint_as_float(hv.z & 0xFFFF0000u), a5); \
    a6 = fmaf(ev, __uint_as_float(hv.w << 16),         a6); \
    a7 = fmaf(ev, __uint_as_float(hv.w & 0xFFFF0000u), a7)

// shared-memory layout for the linear body (aliased by the stage path)
struct LinSmem {
    float Ws[F * F];          // 16 KB
    float xs[32 * XSP];       // 8.7 KB
    float asv[F], adv[F];
};

// ---------------------------------------------------------------------------
// Linear body: h16 = bf16(x @ W) ; as_ = (xW).a_src ; ad_ = (xW).a_dst
// 32 nodes / block; 8 lanes per node, 8 output cols per lane.
// ---------------------------------------------------------------------------
__device__ __forceinline__ void linear_body(
    LinSmem& sm,
    const float* __restrict__ x, const float* __restrict__ W,
    const float* __restrict__ a_src, const float* __restrict__ a_dst,
    u16* __restrict__ h16, float* __restrict__ as_, float* __restrict__ ad_,
    int blk)
{
    const int tid = threadIdx.x;
    const int n   = tid >> 3;          // node within block 0..31
    const int c0  = (tid & 7) * 8;     // output col base
    const int node = blk * 32 + n;
    const bool valid = node < NNODES;

    for (int i = tid * 4; i < F * F; i += 1024)
        *(float4*)&sm.Ws[i] = *(const float4*)&W[i];
    if (tid < F) { sm.asv[tid] = a_src[tid]; sm.adv[tid] = a_dst[tid]; }
    if (valid) {
        const float4 v0 = *(const float4*)&x[(size_t)node * F + c0];
        const float4 v1 = *(const float4*)&x[(size_t)node * F + c0 + 4];
        *(float4*)&sm.xs[n * XSP + c0]     = v0;
        *(float4*)&sm.xs[n * XSP + c0 + 4] = v1;
    }
    __syncthreads();

    float o0=0.f,o1=0.f,o2=0.f,o3=0.f,o4=0.f,o5=0.f,o6=0.f,o7=0.f;
#pragma unroll 8
    for (int k = 0; k < F; ++k) {
        const float xv = sm.xs[n * XSP + k];
        const float4 wa = *(const float4*)&sm.Ws[k * F + c0];
        const float4 wb = *(const float4*)&sm.Ws[k * F + c0 + 4];
        o0 = fmaf(xv, wa.x, o0); o1 = fmaf(xv, wa.y, o1);
        o2 = fmaf(xv, wa.z, o2); o3 = fmaf(xv, wa.w, o3);
        o4 = fmaf(xv, wb.x, o4); o5 = fmaf(xv, wb.y, o5);
        o6 = fmaf(xv, wb.z, o6); o7 = fmaf(xv, wb.w, o7);
    }

    float vs = o0*sm.asv[c0]   + o1*sm.asv[c0+1] + o2*sm.asv[c0+2] + o3*sm.asv[c0+3]
             + o4*sm.asv[c0+4] + o5*sm.asv[c0+5] + o6*sm.asv[c0+6] + o7*sm.asv[c0+7];
    float vd = o0*sm.adv[c0]   + o1*sm.adv[c0+1] + o2*sm.adv[c0+2] + o3*sm.adv[c0+3]
             + o4*sm.adv[c0+4] + o5*sm.adv[c0+5] + o6*sm.adv[c0+6] + o7*sm.adv[c0+7];
    vs += __shfl_xor(vs, 1, 64); vs += __shfl_xor(vs, 2, 64); vs += __shfl_xor(vs, 4, 64);
    vd += __shfl_xor(vd, 1, 64); vd += __shfl_xor(vd, 2, 64); vd += __shfl_xor(vd, 4, 64);

    if (valid) {
        if ((tid & 7) == 0) { as_[node] = vs; ad_[node] = vd; }
        uint4 p;
        p.x = f2bf2(o0, o1); p.y = f2bf2(o2, o3);
        p.z = f2bf2(o4, o5); p.w = f2bf2(o6, o7);
        *(uint4*)&h16[(size_t)node * F + c0] = p;
    }
}

// ---------------------------------------------------------------------------
// K1: blocks [0,SBLK): stage edges into fixed-CAP bucket regions (single
//     pass, (src,dst) in registers). blocks [SBLK..): layer-1 linear.
//     After this kernel, gcur[b] = edge count of bucket b.
// ---------------------------------------------------------------------------
__global__ __launch_bounds__(256) void stage_linear1(
    const float* __restrict__ x, const float* __restrict__ W,
    const float* __restrict__ a_src, const float* __restrict__ a_dst,
    u16* __restrict__ h16, float* __restrict__ as_, float* __restrict__ ad_,
    const int* __restrict__ src, const int* __restrict__ dst,
    int* __restrict__ gcur, u32* __restrict__ stg)
{
    __shared__ LinSmem sm;
    if (blockIdx.x < SBLK) {
        int* cnt  = (int*)&sm;          // NB ints
        int* lcur = cnt + NB;           // NB ints (aliases sm)
        for (int i = threadIdx.x; i < NB; i += 256) cnt[i] = 0;
        __syncthreads();
        const int base = blockIdx.x * SEPB;
        int es[SIT], ed[SIT];
#pragma unroll
        for (int it = 0; it < SIT; ++it) {
            const int e = base + it * 256 + threadIdx.x;
            if (e < ETOT) {
                int s, d;
                if (e < NEDGES) { s = src[e]; d = dst[e]; }
                else            { s = e - NEDGES; d = s; }
                es[it] = s; ed[it] = d;
                atomicAdd(&cnt[d >> 6], 1);
            } else {
                ed[it] = -1; es[it] = 0;
            }
        }
        __syncthreads();
        for (int i = threadIdx.x; i < NB; i += 256)
            lcur[i] = cnt[i] ? (i * CAP + atomicAdd(&gcur[i], cnt[i])) : 0;
        __syncthreads();
#pragma unroll
        for (int it = 0; it < SIT; ++it) {
            if (ed[it] >= 0) {
                const int p = atomicAdd(&lcur[ed[it] >> 6], 1);
                stg[p] = ((u32)(ed[it] & 63) << 16) | (u32)es[it];
            }
        }
        return;
    }
    linear_body(sm, x, W, a_src, a_dst, h16, as_, ad_, blockIdx.x - SBLK);
}

// ---------------------------------------------------------------------------
// K2/K3: per-bucket fused {CSR build in LDS + per-edge attention} + softmax
// aggregate + bias + LeakyReLU(0.01).
// Block = 64 nodes (one bucket), 512 threads, 8 lanes per node.
// Build: hist -> scan -> scatter packed (f16(ev)<<16 | src) into LDS csrE;
//        ev computed ONCE per edge here (was 8x in hot loop).
// Agg:   per edge-lane: 1 LDS broadcast read + 1 global 16B h-row gather.
// MODE 0 epilogue: fused layer-2 linear -> bf16 h2 + attention dots.
// MODE 1 epilogue: + residual, f32 out.
// ---------------------------------------------------------------------------
template<int MODE>
__global__ __launch_bounds__(512) void gat_agg(
    const int* __restrict__ gcur, const u32* __restrict__ stg,
    const u16* __restrict__ hin,
    const float* __restrict__ as_, const float* __restrict__ ad_,
    const float* __restrict__ bias,
    const float* __restrict__ Wn, const float* __restrict__ an_s,
    const float* __restrict__ an_d,
    u16* __restrict__ hout, float* __restrict__ as_out, float* __restrict__ ad_out,
    const float* __restrict__ resid, float* __restrict__ out)
{
    __shared__ u32  csrE[CAP];
    __shared__ int  cnt[64];     // hist, then scatter cursor
    __shared__ int  rp[64];      // local exclusive rowptr
    __shared__ float advn[64];   // ad_ for bucket nodes
    __shared__ float Ws[MODE == 0 ? F * F : 1];
    __shared__ float asv[MODE == 0 ? F : 1], adv[MODE == 0 ? F : 1];
    __shared__ float xs[MODE == 0 ? 64 * XSP : 1];

    const int tid   = threadIdx.x;
    const int b     = blockIdx.x;
    const int nbase = b << 6;
    const int nr    = (NNODES - nbase < 64) ? (NNODES - nbase) : 64;
    const int m     = gcur[b];

    if (tid < 64) {
        cnt[tid]  = 0;
        advn[tid] = (tid < nr) ? ad_[nbase + tid] : 0.f;
    }
    if constexpr (MODE == 0) {
        for (int i = tid * 4; i < F * F; i += 2048)
            *(float4*)&Ws[i] = *(const float4*)&Wn[i];
        if (tid < F) { asv[tid] = an_s[tid]; adv[tid] = an_d[tid]; }
    }
    __syncthreads();

    // ---- build: hist
    for (int i = tid; i < m; i += 512)
        atomicAdd(&cnt[stg[b * CAP + i] >> 16], 1);
    __syncthreads();
    // ---- scan (wave 0)
    if (tid < 64) {
        const int v = cnt[tid];
        int incl = v;
#pragma unroll
        for (int off = 1; off < 64; off <<= 1) {
            const int t = __shfl_up(incl, off, 64);
            if (tid >= off) incl += t;
        }
        rp[tid]  = incl - v;       // local exclusive prefix
        cnt[tid] = incl - v;       // scatter cursor
    }
    __syncthreads();
    // ---- scatter + per-edge attention weight (once per edge)
    for (int i = tid; i < m; i += 512) {
        const u32 pk = stg[b * CAP + i];
        const int d6 = pk >> 16;
        const int s  = pk & 0xFFFFu;
        float r = as_[s] + advn[d6];
        r = (r > 0.f) ? r : 0.2f * r;
        const float ev = __expf(r);
        const int pos = atomicAdd(&cnt[d6], 1);
        csrE[pos] = ((u32)__half_as_ushort(__float2half(ev)) << 16) | (u32)s;
    }
    __syncthreads();

    // ---- aggregate: 8 lanes per node
    const int n   = tid >> 3;          // node 0..63
    const int l   = tid & 7;           // 16B chunk of the 128B bf16 row
    const int beg = rp[n];
    const int deg = cnt[n] - rp[n];    // cursor advanced by exactly deg

    float a0=0.f,a1=0.f,a2=0.f,a3=0.f,a4=0.f,a5=0.f,a6=0.f,a7=0.f;
    float z = 0.f;
    const int nfull = deg & ~3;
    int i = 0;
    for (; i < nfull; i += 4) {
        const u32 p1 = csrE[beg + i];
        const u32 p2 = csrE[beg + i + 1];
        const u32 p3 = csrE[beg + i + 2];
        const u32 p4 = csrE[beg + i + 3];
        const uint4 h1 = ((const uint4*)(hin + (size_t)(p1 & 0xFFFFu) * F))[l];
        const uint4 h2 = ((const uint4*)(hin + (size_t)(p2 & 0xFFFFu) * F))[l];
        const uint4 h3 = ((const uint4*)(hin + (size_t)(p3 & 0xFFFFu) * F))[l];
        const uint4 h4 = ((const uint4*)(hin + (size_t)(p4 & 0xFFFFu) * F))[l];
        const float e1 = __half2float(__ushort_as_half((u16)(p1 >> 16)));
        const float e2 = __half2float(__ushort_as_half((u16)(p2 >> 16)));
        const float e3 = __half2float(__ushort_as_half((u16)(p3 >> 16)));
        const float e4 = __half2float(__ushort_as_half((u16)(p4 >> 16)));
        z += (e1 + e2) + (e3 + e4);
        ACC8(e1, h1); ACC8(e2, h2); ACC8(e3, h3); ACC8(e4, h4);
    }
    if (i < deg) {                      // masked tail (1..3 edges)
        const int j2 = (i + 1 < deg) ? (i + 1) : i;
        const int j3 = (i + 2 < deg) ? (i + 2) : i;
        const u32 p1 = csrE[beg + i];
        const u32 p2 = csrE[beg + j2];
        const u32 p3 = csrE[beg + j3];
        const uint4 h1 = ((const uint4*)(hin + (size_t)(p1 & 0xFFFFu) * F))[l];
        const uint4 h2 = ((const uint4*)(hin + (size_t)(p2 & 0xFFFFu) * F))[l];
        const uint4 h3 = ((const uint4*)(hin + (size_t)(p3 & 0xFFFFu) * F))[l];
        const float e1 = __half2float(__ushort_as_half((u16)(p1 >> 16)));
        const float e2 = (i + 1 < deg) ? __half2float(__ushort_as_half((u16)(p2 >> 16))) : 0.f;
        const float e3 = (i + 2 < deg) ? __half2float(__ushort_as_half((u16)(p3 >> 16))) : 0.f;
        z += e1 + e2 + e3;
        ACC8(e1, h1); ACC8(e2, h2); ACC8(e3, h3);
    }

    const float inv = 1.f / (z + 1e-16f);
    const float4 b0v = *(const float4*)&bias[l * 8];
    const float4 b1v = *(const float4*)&bias[l * 8 + 4];
    float v0 = a0 * inv + b0v.x, v1 = a1 * inv + b0v.y;
    float v2 = a2 * inv + b0v.z, v3 = a3 * inv + b0v.w;
    float v4 = a4 * inv + b1v.x, v5 = a5 * inv + b1v.y;
    float v6 = a6 * inv + b1v.z, v7 = a7 * inv + b1v.w;
    v0 = (v0 > 0.f) ? v0 : 0.01f * v0;  v1 = (v1 > 0.f) ? v1 : 0.01f * v1;
    v2 = (v2 > 0.f) ? v2 : 0.01f * v2;  v3 = (v3 > 0.f) ? v3 : 0.01f * v3;
    v4 = (v4 > 0.f) ? v4 : 0.01f * v4;  v5 = (v5 > 0.f) ? v5 : 0.01f * v5;
    v6 = (v6 > 0.f) ? v6 : 0.01f * v6;  v7 = (v7 > 0.f) ? v7 : 0.01f * v7;

    if constexpr (MODE == 0) {
        {
            float4 w0; w0.x = v0; w0.y = v1; w0.z = v2; w0.w = v3;
            float4 w1; w1.x = v4; w1.y = v5; w1.z = v6; w1.w = v7;
            const int xb = n * XSP + l * 8;
            *(float4*)&xs[xb]     = w0;
            *(float4*)&xs[xb + 4] = w1;
        }
        __syncthreads();

        const int nb2 = tid >> 3;          // node 0..63
        const int c0  = (tid & 7) * 8;     // 8 output cols
        float o0=0.f,o1=0.f,o2=0.f,o3=0.f,o4=0.f,o5=0.f,o6=0.f,o7=0.f;
#pragma unroll 8
        for (int k = 0; k < F; ++k) {
            const float xv = xs[nb2 * XSP + k];
            const float4 wa = *(const float4*)&Ws[k * F + c0];
            const float4 wb = *(const float4*)&Ws[k * F + c0 + 4];
            o0 = fmaf(xv, wa.x, o0); o1 = fmaf(xv, wa.y, o1);
            o2 = fmaf(xv, wa.z, o2); o3 = fmaf(xv, wa.w, o3);
            o4 = fmaf(xv, wb.x, o4); o5 = fmaf(xv, wb.y, o5);
            o6 = fmaf(xv, wb.z, o6); o7 = fmaf(xv, wb.w, o7);
        }
        float vs = o0*asv[c0]   + o1*asv[c0+1] + o2*asv[c0+2] + o3*asv[c0+3]
                 + o4*asv[c0+4] + o5*asv[c0+5] + o6*asv[c0+6] + o7*asv[c0+7];
        float vd = o0*adv[c0]   + o1*adv[c0+1] + o2*adv[c0+2] + o3*adv[c0+3]
                 + o4*adv[c0+4] + o5*adv[c0+5] + o6*adv[c0+6] + o7*adv[c0+7];
        vs += __shfl_xor(vs, 1, 64); vs += __shfl_xor(vs, 2, 64); vs += __shfl_xor(vs, 4, 64);
        vd += __shfl_xor(vd, 1, 64); vd += __shfl_xor(vd, 2, 64); vd += __shfl_xor(vd, 4, 64);
        if (nb2 < nr) {
            const int node2 = nbase + nb2;
            if ((tid & 7) == 0) { as_out[node2] = vs; ad_out[node2] = vd; }
            uint4 p;
            p.x = f2bf2(o0, o1); p.y = f2bf2(o2, o3);
            p.z = f2bf2(o4, o5); p.w = f2bf2(o6, o7);
            *(uint4*)&hout[(size_t)node2 * F + c0] = p;
        }
    } else {
        if (n < nr) {
            const int node = nbase + n;
            const float4 r0 = *(const float4*)(resid + (size_t)node * F + l * 8);
            const float4 r1 = *(const float4*)(resid + (size_t)node * F + l * 8 + 4);
            float4 o0, o1;
            o0.x = v0 + r0.x; o0.y = v1 + r0.y; o0.z = v2 + r0.z; o0.w = v3 + r0.w;
            o1.x = v4 + r1.x; o1.y = v5 + r1.y; o1.z = v6 + r1.z; o1.w = v7 + r1.w;
            *(float4*)(out + (size_t)node * F + l * 8)     = o0;
            *(float4*)(out + (size_t)node * F + l * 8 + 4) = o1;
        }
    }
}

extern "C" void kernel_launch(void* const* d_in, const int* in_sizes, int n_in,
                              void* d_out, int out_size, void* d_ws, size_t ws_size,
                              hipStream_t stream)
{
    const float* x   = (const float*)d_in[0];
    const int*   ei  = (const int*)  d_in[1];   // [2, NEDGES] row-major
    const float* W0  = (const float*)d_in[2];
    const float* as0 = (const float*)d_in[3];
    const float* ad0 = (const float*)d_in[4];
    const float* b0  = (const float*)d_in[5];
    const float* W1  = (const float*)d_in[6];
    const float* as1 = (const float*)d_in[7];
    const float* ad1 = (const float*)d_in[8];
    const float* b1  = (const float*)d_in[9];
    float* out = (float*)d_out;

    const int* src = ei;
    const int* dst = ei + NEDGES;

    // workspace carve-up (~18 MB)
    char* ws = (char*)d_ws;
    u16*   h16    = (u16*)ws;   ws += (size_t)NNODES * F * 2;   // layer-1 h
    u16*   h2_16  = (u16*)ws;   ws += (size_t)NNODES * F * 2;   // layer-2 h
    float* as_    = (float*)ws; ws += (size_t)NNODES * 4;
    float* ad_    = (float*)ws; ws += (size_t)NNODES * 4;
    float* as2    = (float*)ws; ws += (size_t)NNODES * 4;
    float* ad2    = (float*)ws; ws += (size_t)NNODES * 4;
    int*   gcur   = (int*)ws;   ws += (size_t)NB * 4;
    u32*   stg    = (u32*)ws;   ws += (size_t)NB * CAP * 4;

    hipMemsetAsync(gcur, 0, (size_t)NB * 4, stream);
    stage_linear1<<<SBLK + LIN_BLOCKS, 256, 0, stream>>>(
        x, W0, as0, ad0, h16, as_, ad_, src, dst, gcur, stg);

    // layer-1 aggregate (+LDS CSR build) + fused layer-2 linear
    gat_agg<0><<<NB, 512, 0, stream>>>(
        gcur, stg, h16, as_, ad_, b0,
        W1, as1, ad1, h2_16, as2, ad2, nullptr, nullptr);
    // layer-2 aggregate (+LDS CSR build) + residual
    gat_agg<1><<<NB, 512, 0, stream>>>(
        gcur, stg, h2_16, as2, ad2, b1,
        nullptr, nullptr, nullptr, nullptr, nullptr, nullptr, x, out);
}